// Round 9
// baseline (238.532 us; speedup 1.0000x reference)
//
#include <hip/hip_runtime.h>

typedef unsigned short u16;
typedef unsigned int u32;
typedef __attribute__((ext_vector_type(8))) short bf16x8;
typedef __attribute__((ext_vector_type(4))) float f32x4;

__device__ __forceinline__ u16 f2b(float f) {
    union { float f; u32 u; } v; v.f = f;
    return (u16)((v.u + 0x7FFF + ((v.u >> 16) & 1)) >> 16);  // RNE
}

__device__ __forceinline__ void glds16(const u16* g, u16* l) {
    __builtin_amdgcn_global_load_lds(
        (const __attribute__((address_space(1))) void*)g,
        (__attribute__((address_space(3))) void*)l, 16, 0, 0);
}

// ---------------------------------------------------------------------------
// Fused prep: grid (1024, 1, 5).
//   z<3 : fp32 -> bf16 flat cast of Q/K/V (n4 = 1048576 float4's each).
//   z==3: per-head weight transpose-cast fp32 [16][1024][64] -> [16][64][1024]
//         (x<768: r0i = x&15, sel = x>>8, hz = (x>>4)&15).
//   z==4: Wo transpose-cast fp32 [1024][1024] -> ^T (x<256).
// NOTE: inputs are cast to bf16 UNMODIFIED — the harness reference quantizes
// the raw inputs; pre-scaling before the cast breaks cancellation (round 5).
// ---------------------------------------------------------------------------
__global__ __launch_bounds__(256) void prep(
    const float* __restrict__ Q, const float* __restrict__ K,
    const float* __restrict__ V,
    const float* __restrict__ Wq, const float* __restrict__ Wk,
    const float* __restrict__ Wv, const float* __restrict__ Wo,
    u16* __restrict__ Qb, u16* __restrict__ Kb, u16* __restrict__ Vb,
    u16* __restrict__ WqT, u16* __restrict__ WkT, u16* __restrict__ WvT,
    u16* __restrict__ WoT)
{
    __shared__ float t[64][68];
    const int z = blockIdx.z, x = blockIdx.x, tid = threadIdx.x;

    if (z < 3) {
        const float* in = (z == 0) ? Q : (z == 1) ? K : V;
        u16* out = (z == 0) ? Qb : (z == 1) ? Kb : Vb;
        const int n4 = 1048576;
        const int stride = 1024 * 256;
        for (int i = x * 256 + tid; i < n4; i += stride) {
            float4 v = ((const float4*)in)[i];
            ushort4 o;
            o.x = f2b(v.x); o.y = f2b(v.y); o.z = f2b(v.z); o.w = f2b(v.w);
            ((ushort4*)out)[i] = o;
        }
        return;
    }

    const int rr = tid >> 4, c4 = (tid & 15) * 4;

    if (z == 3) {
        if (x >= 768) return;
        const int sel = x >> 8, hz = (x >> 4) & 15;
        const float* in = (sel == 0) ? Wq : (sel == 1) ? Wk : Wv;
        u16* out = (sel == 0) ? WqT : (sel == 1) ? WkT : WvT;
        const long mb = (long)hz * 65536;
        const int r0 = (x & 15) * 64;

        #pragma unroll
        for (int p = 0; p < 4; ++p) {
            float4 v = *(const float4*)(in + mb + (long)(r0 + p * 16 + rr) * 64 + c4);
            *(float4*)&t[p * 16 + rr][c4] = v;
        }
        __syncthreads();
        #pragma unroll
        for (int p = 0; p < 4; ++p) {
            const int oc = p * 16 + rr;
            const int r4 = (tid & 15) * 4;
            ushort4 o;
            o.x = f2b(t[r4 + 0][oc]); o.y = f2b(t[r4 + 1][oc]);
            o.z = f2b(t[r4 + 2][oc]); o.w = f2b(t[r4 + 3][oc]);
            *(ushort4*)(out + mb + (long)oc * 1024 + r0 + r4) = o;
        }
        return;
    }

    // z == 4: Wo
    if (x >= 256) return;
    const int r0 = (x & 15) * 64, c0 = (x >> 4) * 64;
    #pragma unroll
    for (int p = 0; p < 4; ++p) {
        float4 v = *(const float4*)(Wo + (long)(r0 + p * 16 + rr) * 1024 + c0 + c4);
        *(float4*)&t[p * 16 + rr][c4] = v;
    }
    __syncthreads();
    #pragma unroll
    for (int p = 0; p < 4; ++p) {
        const int oc = p * 16 + rr;
        const int r4 = (tid & 15) * 4;
        ushort4 o;
        o.x = f2b(t[r4 + 0][oc]); o.y = f2b(t[r4 + 1][oc]);
        o.z = f2b(t[r4 + 2][oc]); o.w = f2b(t[r4 + 3][oc]);
        *(ushort4*)(WoT + (long)(c0 + oc) * 1024 + r0 + r4) = o;
    }
}

// ---------------------------------------------------------------------------
// GEMM body shared by proj3 / gemm_out. v3: BK=32, 3-buffer rotation with
// counted vmcnt(4) + raw s_barrier (attn-v5 pattern, HW-proven r4/r8).
// LDS 48 KB -> 3 blocks/CU -> all 768 proj3 blocks resident (no tail round),
// 12 waves/CU. Swizzle (mod-4 chunks): store chunk c of row r at
// c ^ (r&3) ^ ((r>>2)&1); read pos = quad ^ (fr&3) ^ ((fr>>2)&1) -> lanes
// 0-15 hit 8 bank-groups x2 = 2-way (free; model validated by r2's zero
// conflicts). K-accumulation order identical to BK=64 version (bit-exact).
// Grid mapping: x = m-tile (32), y = n-tile (8) for XCD L2 locality.
// ---------------------------------------------------------------------------
#define GEMM_STAGE(A_, BT_, p_, k_)                                            \
    _Pragma("unroll")                                                          \
    for (int i2 = 0; i2 < 2; ++i2) {                                           \
        const int i = w * 2 + i2;                                              \
        glds16(A_ + ga + (long)i * 16 * 1024 + (k_), &As[p_][i * 512]);        \
        glds16(BT_ + gb + (long)i * 16 * 1024 + (k_), &Bs[p_][i * 512]);       \
    }

#define GEMM_CORE(A_, BT_)                                                     \
    __shared__ u16 As[3][128 * 32];                                            \
    __shared__ u16 Bs[3][128 * 32];                                            \
    const int tid = threadIdx.x, lane = tid & 63, w = tid >> 6;                \
    const int m0 = blockIdx.x * 128, n0 = blockIdx.y * 128;                    \
    const int wm = (w >> 1) * 64, wn = (w & 1) * 64;                           \
    const int fr = lane & 15, quad = lane >> 4;                                \
    f32x4 acc[4][4];                                                           \
    const f32x4 zero = {0.f, 0.f, 0.f, 0.f};                                   \
    _Pragma("unroll")                                                          \
    for (int mi = 0; mi < 4; ++mi)                                             \
        _Pragma("unroll")                                                      \
        for (int ni = 0; ni < 4; ++ni) acc[mi][ni] = zero;                     \
    /* staging: 16 rows x 32 cols per glds group; srow = lane>>2 (0..15), */   \
    /* source chunk = (lane&3) ^ (srow&3) ^ ((srow>>2)&1)                  */  \
    const int srow = lane >> 2;                                                \
    const int schk = (lane & 3) ^ (srow & 3) ^ ((srow >> 2) & 1);              \
    const long ga = (long)(m0 + srow) * 1024 + schk * 8;                       \
    const long gb = (long)(n0 + srow) * 1024 + schk * 8;                       \
    const int pos = ((quad ^ (fr & 3) ^ ((fr >> 2) & 1))) * 8;                 \
    GEMM_STAGE(A_, BT_, 0, 0)                                                  \
    GEMM_STAGE(A_, BT_, 1, 32)                                                 \
    for (int k0 = 0; k0 < 1024; k0 += 32) {                                    \
        const int it = k0 >> 5;                                                \
        const int p = it % 3;                                                  \
        if (k0 + 32 < 1024) {                                                  \
            __asm__ volatile("s_waitcnt vmcnt(4)" ::: "memory");               \
        } else {                                                               \
            __asm__ volatile("s_waitcnt vmcnt(0)" ::: "memory");               \
        }                                                                      \
        __builtin_amdgcn_s_barrier();                                          \
        __asm__ volatile("" ::: "memory");                                     \
        __builtin_amdgcn_sched_barrier(0);                                     \
        if (k0 + 64 < 1024) { GEMM_STAGE(A_, BT_, (it + 2) % 3, k0 + 64) }     \
        __builtin_amdgcn_s_setprio(1);                                         \
        bf16x8 af[4], bfr[4];                                                  \
        _Pragma("unroll")                                                      \
        for (int mi = 0; mi < 4; ++mi)                                         \
            af[mi] = *(const bf16x8*)&As[p][(wm + mi * 16 + fr) * 32 + pos];   \
        _Pragma("unroll")                                                      \
        for (int ni = 0; ni < 4; ++ni)                                         \
            bfr[ni] = *(const bf16x8*)&Bs[p][(wn + ni * 16 + fr) * 32 + pos];  \
        _Pragma("unroll")                                                      \
        for (int mi = 0; mi < 4; ++mi)                                         \
            _Pragma("unroll")                                                  \
            for (int ni = 0; ni < 4; ++ni)                                     \
                acc[mi][ni] = __builtin_amdgcn_mfma_f32_16x16x32_bf16(         \
                    af[mi], bfr[ni], acc[mi][ni], 0, 0, 0);                    \
        __builtin_amdgcn_s_setprio(0);                                         \
    }

// Projections (z: 0=Q, 1=K, 2=V). OUT: z<2 -> [bh][s][64]; z==2 -> [bh][64][s]
__global__ __launch_bounds__(256) void proj3(
    const u16* __restrict__ Qb, const u16* __restrict__ Kb,
    const u16* __restrict__ Vb,
    const u16* __restrict__ WqT, const u16* __restrict__ WkT,
    const u16* __restrict__ WvT,
    const float* __restrict__ bq, const float* __restrict__ bk,
    const float* __restrict__ bv,
    u16* __restrict__ QWb, u16* __restrict__ KWb, u16* __restrict__ VWb)
{
    const int z = blockIdx.z;
    const u16* A  = (z == 0) ? Qb : (z == 1) ? Kb : Vb;
    const u16* BT = (z == 0) ? WqT : (z == 1) ? WkT : WvT;
    const float* bias = (z == 0) ? bq : (z == 1) ? bk : bv;
    u16* Cu = (z == 0) ? QWb : (z == 1) ? KWb : VWb;

    GEMM_CORE(A, BT)

    #pragma unroll
    for (int mi = 0; mi < 4; ++mi) {
        #pragma unroll
        for (int ni = 0; ni < 4; ++ni) {
            const int mB = m0 + wm + mi * 16 + quad * 4;   // r = 0 row
            const int c  = n0 + wn + ni * 16 + fr;
            const int b = mB >> 11, s = mB & 2047, h = c >> 6, k = c & 63;
            const float bi = bias[c];
            if (z != 2) {
                #pragma unroll
                for (int r = 0; r < 4; ++r)
                    Cu[((long)(b * 16 + h) * 2048 + s + r) * 64 + k] =
                        f2b(acc[mi][ni][r] + bi);
            } else {
                ushort4 o;
                o.x = f2b(acc[mi][ni][0] + bi);
                o.y = f2b(acc[mi][ni][1] + bi);
                o.z = f2b(acc[mi][ni][2] + bi);
                o.w = f2b(acc[mi][ni][3] + bi);
                *(ushort4*)&Cu[((long)(b * 16 + h) * 64 + k) * 2048 + s] = o;
            }
        }
    }
}

// Output projection: fp32 out = ctx(bf16) @ WoT^T + bo
__global__ __launch_bounds__(256) void gemm_out(
    const u16* __restrict__ A, const u16* __restrict__ BT,
    const float* __restrict__ bias, float* __restrict__ Cf)
{
    GEMM_CORE(A, BT)

    #pragma unroll
    for (int mi = 0; mi < 4; ++mi) {
        #pragma unroll
        for (int ni = 0; ni < 4; ++ni) {
            #pragma unroll
            for (int r = 0; r < 4; ++r) {
                const int m = m0 + wm + mi * 16 + quad * 4 + r;
                const int c = n0 + wn + ni * 16 + fr;
                Cf[(long)m * 1024 + c] = acc[mi][ni][r] + bias[c];
            }
        }
    }
}

// ---------------------------------------------------------------------------
// MFMA flash attention — BYTE-IDENTICAL to round-8's passing version.
//   QW/KW: [bh][2048][64]; VW: [bh][64][2048] (bf16).
//   Block = 4 waves, 128 q rows (32 per wave as 2 sets of 16).
//   Distance-2 prefetch over 3 LDS buffers, counted vmcnt(4) + raw s_barrier.
//   XCD colocate remap: id%8 = XCD; 4 heads x 16 q-tiles per XCD.
//   ps is LINEAR stride-72 (XOR relayout failed on HW in r5/r6 — burned).
//   Swapped QK^T (mfma(K,Q) -> t-consecutive regs -> cvt_pk + b64 P store),
//   s_setprio around MFMA clusters. Non-centered softmax, l via ones-MFMA;
//   ctx scaled by 1/(l*128).
// ---------------------------------------------------------------------------
__global__ __launch_bounds__(256) void attn_mfma(
    const u16* __restrict__ QW, const u16* __restrict__ KW,
    const u16* __restrict__ VW, u16* __restrict__ ctxb)
{
    __shared__ u16 kt[3][64 * 64];   // [buf][t][k] swizzled, 24 KB
    __shared__ u16 vt[3][64 * 64];   // [buf][d][t] swizzled, 24 KB
    __shared__ u16 ps[4][32 * 72];   // per-wave P [q][t], stride 72, 18 KB

    const int tid = threadIdx.x, lane = tid & 63, w = tid >> 6;
    // XCD colocate: id%8 is the XCD (round-robin dispatch). Bijection:
    // bh = (id&7)*4 + ((id>>3)&3), qt = id>>5  (512 blocks total).
    const int id = blockIdx.x + gridDim.x * blockIdx.y;
    const int bh = (id & 7) * 4 + ((id >> 3) & 3);
    const int q0 = (id >> 5) * 128;
    const int b = bh >> 4, h = bh & 15;
    const int fr = lane & 15, quad = lane >> 4;
    const int f7 = fr & 7;

    // Q fragments (B-operand of swapped QK^T): 2 q-sets of 16 rows, q = fr
    bf16x8 aQ[2][2];
    #pragma unroll
    for (int s = 0; s < 2; ++s) {
        const u16* qp = QW + ((long)bh * 2048 + q0 + w * 32 + s * 16 + fr) * 64;
        aQ[s][0] = *(const bf16x8*)(qp + quad * 8);
        aQ[s][1] = *(const bf16x8*)(qp + 32 + quad * 8);
    }

    const f32x4 zero = {0.f, 0.f, 0.f, 0.f};
    f32x4 acc[2][4], lac[2];
    #pragma unroll
    for (int s = 0; s < 2; ++s) {
        lac[s] = zero;
        #pragma unroll
        for (int d = 0; d < 4; ++d) acc[s][d] = zero;
    }
    bf16x8 bones;
    #pragma unroll
    for (int j = 0; j < 8; ++j) bones[j] = (short)0x3F80;  // bf16 1.0

    const int srow = lane >> 3;
    const int schk = (lane & 7) ^ (srow & 7);   // swizzled source chunk
    const long kgb = (long)bh * (2048 * 64);
    const long vgb = (long)bh * (64 * 2048);

#define ATTN_STAGE(p_, t_)                                                    \
    _Pragma("unroll")                                                         \
    for (int i2 = 0; i2 < 2; ++i2) {                                          \
        const int i = w * 2 + i2;                                             \
        glds16(KW + kgb + (long)((t_) + i * 8 + srow) * 64 + schk * 8,        \
               &kt[p_][i * 512]);                                             \
        glds16(VW + vgb + (long)(i * 8 + srow) * 2048 + (t_) + schk * 8,      \
               &vt[p_][i * 512]);                                             \
    }

    // Prologue: tiles 0 and 1 in flight (8 outstanding vm ops/wave).
    ATTN_STAGE(0, 0)
    ATTN_STAGE(1, 64)

    const int pos0 = (quad ^ f7) * 8;      // swizzled chunk {quad}
    const int pos1 = pos0 ^ 32;            // swizzled chunk {quad+4}
    u16* pw = ps[w];

    for (int t0 = 0; t0 < 2048; t0 += 64) {
        const int it = t0 >> 6;
        const int p = it % 3;

        // Counted wait: retire current tile's 4 loads; next tile's 4 stay
        // in flight across the barrier (T4). Last iter fully drains.
        if (t0 + 64 < 2048) {
            __asm__ volatile("s_waitcnt vmcnt(4)" ::: "memory");
        } else {
            __asm__ volatile("s_waitcnt vmcnt(0)" ::: "memory");
        }
        __builtin_amdgcn_s_barrier();
        __asm__ volatile("" ::: "memory");
        __builtin_amdgcn_sched_barrier(0);

        // Stage tile i+2 into the buffer last read at iter i-1 (safe: those
        // reads completed before this barrier).
        if (t0 + 128 < 2048) { ATTN_STAGE((it + 2) % 3, t0 + 128) }

        const u16* ktp = kt[p];
        const u16* vtp = vt[p];

        // ---- swapped QK^T: D[t][q]; lane(fr=q,quad): t = sub*16+quad*4+r
        f32x4 sc[2][4];
        __builtin_amdgcn_s_setprio(1);
        #pragma unroll
        for (int s = 0; s < 2; ++s) {
            #pragma unroll
            for (int sub = 0; sub < 4; ++sub) {
                const int row = (sub * 16 + fr) * 64;
                bf16x8 k0 = *(const bf16x8*)&ktp[row + pos0];
                bf16x8 k1 = *(const bf16x8*)&ktp[row + pos1];
                f32x4 z = __builtin_amdgcn_mfma_f32_16x16x32_bf16(k0, aQ[s][0], zero, 0, 0, 0);
                sc[s][sub] = __builtin_amdgcn_mfma_f32_16x16x32_bf16(k1, aQ[s][1], z, 0, 0, 0);
            }
        }
        __builtin_amdgcn_s_setprio(0);

        // ---- exp + packed bf16 convert + vectorized P store (b64) ----
        // q-row = s*16+fr, t = sub*16 + quad*4 + {0..3}
        #pragma unroll
        for (int s = 0; s < 2; ++s) {
            #pragma unroll
            for (int sub = 0; sub < 4; ++sub) {
                float e0 = __expf(sc[s][sub][0]);
                float e1 = __expf(sc[s][sub][1]);
                float e2 = __expf(sc[s][sub][2]);
                float e3 = __expf(sc[s][sub][3]);
                u32 lo, hi;
                asm("v_cvt_pk_bf16_f32 %0, %1, %2" : "=v"(lo) : "v"(e0), "v"(e1));
                asm("v_cvt_pk_bf16_f32 %0, %1, %2" : "=v"(hi) : "v"(e2), "v"(e3));
                uint2 pk2; pk2.x = lo; pk2.y = hi;
                *(uint2*)&pw[(s * 16 + fr) * 72 + sub * 16 + quad * 4] = pk2;
            }
        }
        __asm__ volatile("s_waitcnt lgkmcnt(0)" ::: "memory");

        // ---- l (ones-MFMA) + PV for both q-sets ----
        __builtin_amdgcn_s_setprio(1);
        #pragma unroll
        for (int s = 0; s < 2; ++s) {
            const bf16x8 aP0 = *(const bf16x8*)&pw[(s * 16 + fr) * 72 + quad * 8];
            const bf16x8 aP1 = *(const bf16x8*)&pw[(s * 16 + fr) * 72 + 32 + quad * 8];
            lac[s] = __builtin_amdgcn_mfma_f32_16x16x32_bf16(aP0, bones, lac[s], 0, 0, 0);
            lac[s] = __builtin_amdgcn_mfma_f32_16x16x32_bf16(aP1, bones, lac[s], 0, 0, 0);
            #pragma unroll
            for (int d = 0; d < 4; ++d) {
                const int row = (d * 16 + fr) * 64;
                bf16x8 v0 = *(const bf16x8*)&vtp[row + pos0];
                bf16x8 v1 = *(const bf16x8*)&vtp[row + pos1];
                acc[s][d] = __builtin_amdgcn_mfma_f32_16x16x32_bf16(aP0, v0, acc[s][d], 0, 0, 0);
                acc[s][d] = __builtin_amdgcn_mfma_f32_16x16x32_bf16(aP1, v1, acc[s][d], 0, 0, 0);
            }
        }
        __builtin_amdgcn_s_setprio(0);
        // no trailing barrier: next iter's counted-wait + barrier covers it
    }

    // epilogue: ctx = acc/(l*128), row = q0 + w*32 + s*16 + quad*4 + r
    #pragma unroll
    for (int s = 0; s < 2; ++s) {
        #pragma unroll
        for (int r = 0; r < 4; ++r) {
            const float scl = 1.0f / (lac[s][r] * 128.0f);
            const long row = (long)b * 2048 + q0 + w * 32 + s * 16 + quad * 4 + r;
            #pragma unroll
            for (int d = 0; d < 4; ++d)
                ctxb[row * 1024 + h * 64 + d * 16 + fr] = f2b(acc[s][d][r] * scl);
        }
    }
}

// ---------------------------------------------------------------------------
extern "C" void kernel_launch(void* const* d_in, const int* in_sizes, int n_in,
                              void* d_out, int out_size, void* d_ws, size_t ws_size,
                              hipStream_t stream) {
    (void)in_sizes; (void)n_in; (void)out_size; (void)ws_size;

    const float* Q  = (const float*)d_in[0];
    const float* K  = (const float*)d_in[1];
    const float* V  = (const float*)d_in[2];
    const float* Wq = (const float*)d_in[3];
    const float* bq = (const float*)d_in[4];
    const float* Wk = (const float*)d_in[5];
    const float* bk = (const float*)d_in[6];
    const float* Wv = (const float*)d_in[7];
    const float* bv = (const float*)d_in[8];
    const float* Wo = (const float*)d_in[9];
    const float* bo = (const float*)d_in[10];
    float* out = (float*)d_out;

    u16* ws  = (u16*)d_ws;                // 64 MB total
    u16* Qb  = ws;                        // 4096x1024
    u16* Kb  = Qb  + 4194304;
    u16* Vb  = Kb  + 4194304;
    u16* WqT = Vb  + 4194304;             // [16][64][1024]
    u16* WkT = WqT + 1048576;
    u16* WvT = WkT + 1048576;
    u16* WoT = WvT + 1048576;             // [1024][1024]
    u16* QWb = WoT + 1048576;             // [32][2048][64]
    u16* KWb = QWb + 4194304;             // [32][2048][64]
    u16* VWb = KWb + 4194304;             // [32][64][2048]
    u16* ctx = VWb + 4194304;             // [4096][1024]

    prep<<<dim3(1024, 1, 5), 256, 0, stream>>>(Q, K, V, Wq, Wk, Wv, Wo,
                                               Qb, Kb, Vb, WqT, WkT, WvT, WoT);

    // grid: x = m-tile (32), y = n-tile (8) for XCD L2 locality
    proj3<<<dim3(32, 8, 3), 256, 0, stream>>>(Qb, Kb, Vb, WqT, WkT, WvT,
                                              bq, bk, bv, QWb, KWb, VWb);

    attn_mfma<<<dim3(16, 32), 256, 0, stream>>>(QWb, KWb, VWb, ctx);

    gemm_out<<<dim3(32, 8), 256, 0, stream>>>(ctx, WoT, bo, out);
}

// Round 10
// 223.405 us; speedup vs baseline: 1.0677x; 1.0677x over previous
//
#include <hip/hip_runtime.h>

typedef unsigned short u16;
typedef unsigned int u32;
typedef __attribute__((ext_vector_type(8))) short bf16x8;
typedef __attribute__((ext_vector_type(4))) float f32x4;

__device__ __forceinline__ u16 f2b(float f) {
    union { float f; u32 u; } v; v.f = f;
    return (u16)((v.u + 0x7FFF + ((v.u >> 16) & 1)) >> 16);  // RNE
}

__device__ __forceinline__ void glds16(const u16* g, u16* l) {
    __builtin_amdgcn_global_load_lds(
        (const __attribute__((address_space(1))) void*)g,
        (__attribute__((address_space(3))) void*)l, 16, 0, 0);
}

// ---------------------------------------------------------------------------
// Fused prep: grid (1024, 1, 5).
//   z<3 : fp32 -> bf16 flat cast of Q/K/V (n4 = 1048576 float4's each).
//   z==3: per-head weight transpose-cast fp32 [16][1024][64] -> [16][64][1024]
//         (x<768: r0i = x&15, sel = x>>8, hz = (x>>4)&15).
//   z==4: Wo transpose-cast fp32 [1024][1024] -> ^T (x<256).
// NOTE: inputs are cast to bf16 UNMODIFIED — the harness reference quantizes
// the raw inputs; pre-scaling before the cast breaks cancellation (round 5).
// ---------------------------------------------------------------------------
__global__ __launch_bounds__(256) void prep(
    const float* __restrict__ Q, const float* __restrict__ K,
    const float* __restrict__ V,
    const float* __restrict__ Wq, const float* __restrict__ Wk,
    const float* __restrict__ Wv, const float* __restrict__ Wo,
    u16* __restrict__ Qb, u16* __restrict__ Kb, u16* __restrict__ Vb,
    u16* __restrict__ WqT, u16* __restrict__ WkT, u16* __restrict__ WvT,
    u16* __restrict__ WoT)
{
    __shared__ float t[64][68];
    const int z = blockIdx.z, x = blockIdx.x, tid = threadIdx.x;

    if (z < 3) {
        const float* in = (z == 0) ? Q : (z == 1) ? K : V;
        u16* out = (z == 0) ? Qb : (z == 1) ? Kb : Vb;
        const int n4 = 1048576;
        const int stride = 1024 * 256;
        for (int i = x * 256 + tid; i < n4; i += stride) {
            float4 v = ((const float4*)in)[i];
            ushort4 o;
            o.x = f2b(v.x); o.y = f2b(v.y); o.z = f2b(v.z); o.w = f2b(v.w);
            ((ushort4*)out)[i] = o;
        }
        return;
    }

    const int rr = tid >> 4, c4 = (tid & 15) * 4;

    if (z == 3) {
        if (x >= 768) return;
        const int sel = x >> 8, hz = (x >> 4) & 15;
        const float* in = (sel == 0) ? Wq : (sel == 1) ? Wk : Wv;
        u16* out = (sel == 0) ? WqT : (sel == 1) ? WkT : WvT;
        const long mb = (long)hz * 65536;
        const int r0 = (x & 15) * 64;

        #pragma unroll
        for (int p = 0; p < 4; ++p) {
            float4 v = *(const float4*)(in + mb + (long)(r0 + p * 16 + rr) * 64 + c4);
            *(float4*)&t[p * 16 + rr][c4] = v;
        }
        __syncthreads();
        #pragma unroll
        for (int p = 0; p < 4; ++p) {
            const int oc = p * 16 + rr;
            const int r4 = (tid & 15) * 4;
            ushort4 o;
            o.x = f2b(t[r4 + 0][oc]); o.y = f2b(t[r4 + 1][oc]);
            o.z = f2b(t[r4 + 2][oc]); o.w = f2b(t[r4 + 3][oc]);
            *(ushort4*)(out + mb + (long)oc * 1024 + r0 + r4) = o;
        }
        return;
    }

    // z == 4: Wo
    if (x >= 256) return;
    const int r0 = (x & 15) * 64, c0 = (x >> 4) * 64;
    #pragma unroll
    for (int p = 0; p < 4; ++p) {
        float4 v = *(const float4*)(Wo + (long)(r0 + p * 16 + rr) * 1024 + c0 + c4);
        *(float4*)&t[p * 16 + rr][c4] = v;
    }
    __syncthreads();
    #pragma unroll
    for (int p = 0; p < 4; ++p) {
        const int oc = p * 16 + rr;
        const int r4 = (tid & 15) * 4;
        ushort4 o;
        o.x = f2b(t[r4 + 0][oc]); o.y = f2b(t[r4 + 1][oc]);
        o.z = f2b(t[r4 + 2][oc]); o.w = f2b(t[r4 + 3][oc]);
        *(ushort4*)(WoT + (long)(c0 + oc) * 1024 + r0 + r4) = o;
    }
}

// ---------------------------------------------------------------------------
// GEMM body shared by proj3 / gemm_out — round-8 proven version (BK=64,
// 128x128 tile, 4 waves 2x2, XOR-swizzled LDS chunk^(row&7) — the ONLY
// hardware-validated zero-conflict swizzle, r2 measurement).
// Double-buffered prefetch, single barrier per K-step, s_setprio around MFMA.
// Grid mapping: x = m-tile (32), y = n-tile (8) for XCD L2 locality.
// (r9 lesson: BK=32 + mod-4 swizzle regressed — 3.1M conflicts + halved
//  MFMA-per-barrier amortization. Do not re-attempt paper-only swizzles.)
// ---------------------------------------------------------------------------
#define GEMM_STAGE(A_, BT_, p_, k_)                                            \
    _Pragma("unroll")                                                          \
    for (int i2 = 0; i2 < 4; ++i2) {                                           \
        const int i = w * 4 + i2;                                              \
        glds16(A_ + ga + (long)i * 8 * 1024 + (k_), &As[p_][i * 512]);         \
        glds16(BT_ + gb + (long)i * 8 * 1024 + (k_), &Bs[p_][i * 512]);        \
    }

#define GEMM_CORE(A_, BT_)                                                     \
    __shared__ u16 As[2][128 * 64];                                            \
    __shared__ u16 Bs[2][128 * 64];                                            \
    const int tid = threadIdx.x, lane = tid & 63, w = tid >> 6;                \
    const int m0 = blockIdx.x * 128, n0 = blockIdx.y * 128;                    \
    const int wm = (w >> 1) * 64, wn = (w & 1) * 64;                           \
    const int fr = lane & 15, quad = lane >> 4;                                \
    f32x4 acc[4][4];                                                           \
    const f32x4 zero = {0.f, 0.f, 0.f, 0.f};                                   \
    _Pragma("unroll")                                                          \
    for (int mi = 0; mi < 4; ++mi)                                             \
        _Pragma("unroll")                                                      \
        for (int ni = 0; ni < 4; ++ni) acc[mi][ni] = zero;                     \
    const int srow = lane >> 3;                                                \
    const int schk = (lane & 7) ^ (srow & 7);   /* swizzled source chunk */    \
    const long ga = (long)(m0 + srow) * 1024 + schk * 8;                       \
    const long gb = (long)(n0 + srow) * 1024 + schk * 8;                       \
    const int f7 = fr & 7;                                                     \
    GEMM_STAGE(A_, BT_, 0, 0)                                                  \
    __syncthreads();                                                           \
    for (int k0 = 0; k0 < 1024; k0 += 64) {                                    \
        const int p = (k0 >> 6) & 1;                                           \
        if (k0 + 64 < 1024) { GEMM_STAGE(A_, BT_, p ^ 1, k0 + 64) }            \
        __builtin_amdgcn_s_setprio(1);                                         \
        _Pragma("unroll")                                                      \
        for (int kc = 0; kc < 2; ++kc) {                                       \
            const int pos = ((kc * 4 + quad) ^ f7) * 8;                        \
            bf16x8 af[4], bfr[4];                                              \
            _Pragma("unroll")                                                  \
            for (int mi = 0; mi < 4; ++mi)                                     \
                af[mi] = *(const bf16x8*)&As[p][(wm + mi * 16 + fr) * 64 + pos]; \
            _Pragma("unroll")                                                  \
            for (int ni = 0; ni < 4; ++ni)                                     \
                bfr[ni] = *(const bf16x8*)&Bs[p][(wn + ni * 16 + fr) * 64 + pos]; \
            _Pragma("unroll")                                                  \
            for (int mi = 0; mi < 4; ++mi)                                     \
                _Pragma("unroll")                                              \
                for (int ni = 0; ni < 4; ++ni)                                 \
                    acc[mi][ni] = __builtin_amdgcn_mfma_f32_16x16x32_bf16(     \
                        af[mi], bfr[ni], acc[mi][ni], 0, 0, 0);                \
        }                                                                      \
        __builtin_amdgcn_s_setprio(0);                                         \
        __syncthreads();                                                       \
    }

// Projections (z: 0=Q, 1=K, 2=V). OUT: z<2 -> [bh][s][64]; z==2 -> [bh][64][s]
__global__ __launch_bounds__(256) void proj3(
    const u16* __restrict__ Qb, const u16* __restrict__ Kb,
    const u16* __restrict__ Vb,
    const u16* __restrict__ WqT, const u16* __restrict__ WkT,
    const u16* __restrict__ WvT,
    const float* __restrict__ bq, const float* __restrict__ bk,
    const float* __restrict__ bv,
    u16* __restrict__ QWb, u16* __restrict__ KWb, u16* __restrict__ VWb)
{
    const int z = blockIdx.z;
    const u16* A  = (z == 0) ? Qb : (z == 1) ? Kb : Vb;
    const u16* BT = (z == 0) ? WqT : (z == 1) ? WkT : WvT;
    const float* bias = (z == 0) ? bq : (z == 1) ? bk : bv;
    u16* Cu = (z == 0) ? QWb : (z == 1) ? KWb : VWb;

    GEMM_CORE(A, BT)

    #pragma unroll
    for (int mi = 0; mi < 4; ++mi) {
        #pragma unroll
        for (int ni = 0; ni < 4; ++ni) {
            const int mB = m0 + wm + mi * 16 + quad * 4;   // r = 0 row
            const int c  = n0 + wn + ni * 16 + fr;
            const int b = mB >> 11, s = mB & 2047, h = c >> 6, k = c & 63;
            const float bi = bias[c];
            if (z != 2) {
                #pragma unroll
                for (int r = 0; r < 4; ++r)
                    Cu[((long)(b * 16 + h) * 2048 + s + r) * 64 + k] =
                        f2b(acc[mi][ni][r] + bi);
            } else {
                ushort4 o;
                o.x = f2b(acc[mi][ni][0] + bi);
                o.y = f2b(acc[mi][ni][1] + bi);
                o.z = f2b(acc[mi][ni][2] + bi);
                o.w = f2b(acc[mi][ni][3] + bi);
                *(ushort4*)&Cu[((long)(b * 16 + h) * 64 + k) * 2048 + s] = o;
            }
        }
    }
}

// Output projection: fp32 out = ctx(bf16) @ WoT^T + bo
__global__ __launch_bounds__(256) void gemm_out(
    const u16* __restrict__ A, const u16* __restrict__ BT,
    const float* __restrict__ bias, float* __restrict__ Cf)
{
    GEMM_CORE(A, BT)

    #pragma unroll
    for (int mi = 0; mi < 4; ++mi) {
        #pragma unroll
        for (int ni = 0; ni < 4; ++ni) {
            #pragma unroll
            for (int r = 0; r < 4; ++r) {
                const int m = m0 + wm + mi * 16 + quad * 4 + r;
                const int c = n0 + wn + ni * 16 + fr;
                Cf[(long)m * 1024 + c] = acc[mi][ni][r] + bias[c];
            }
        }
    }
}

// ---------------------------------------------------------------------------
// MFMA flash attention — round-8 passing version (byte-identical).
//   QW/KW: [bh][2048][64]; VW: [bh][64][2048] (bf16).
//   Block = 4 waves, 128 q rows (32 per wave as 2 sets of 16).
//   Distance-2 prefetch over 3 LDS buffers, counted vmcnt(4) + raw s_barrier.
//   XCD colocate remap: id%8 = XCD; 4 heads x 16 q-tiles per XCD.
//   ps is LINEAR stride-72 (XOR relayout failed on HW in r5/r6 — burned).
//   Swapped QK^T (mfma(K,Q) -> t-consecutive regs -> cvt_pk + b64 P store),
//   s_setprio around MFMA clusters. Non-centered softmax, l via ones-MFMA;
//   ctx scaled by 1/(l*128).
// ---------------------------------------------------------------------------
__global__ __launch_bounds__(256) void attn_mfma(
    const u16* __restrict__ QW, const u16* __restrict__ KW,
    const u16* __restrict__ VW, u16* __restrict__ ctxb)
{
    __shared__ u16 kt[3][64 * 64];   // [buf][t][k] swizzled, 24 KB
    __shared__ u16 vt[3][64 * 64];   // [buf][d][t] swizzled, 24 KB
    __shared__ u16 ps[4][32 * 72];   // per-wave P [q][t], stride 72, 18 KB

    const int tid = threadIdx.x, lane = tid & 63, w = tid >> 6;
    // XCD colocate: id%8 is the XCD (round-robin dispatch). Bijection:
    // bh = (id&7)*4 + ((id>>3)&3), qt = id>>5  (512 blocks total).
    const int id = blockIdx.x + gridDim.x * blockIdx.y;
    const int bh = (id & 7) * 4 + ((id >> 3) & 3);
    const int q0 = (id >> 5) * 128;
    const int b = bh >> 4, h = bh & 15;
    const int fr = lane & 15, quad = lane >> 4;
    const int f7 = fr & 7;

    // Q fragments (B-operand of swapped QK^T): 2 q-sets of 16 rows, q = fr
    bf16x8 aQ[2][2];
    #pragma unroll
    for (int s = 0; s < 2; ++s) {
        const u16* qp = QW + ((long)bh * 2048 + q0 + w * 32 + s * 16 + fr) * 64;
        aQ[s][0] = *(const bf16x8*)(qp + quad * 8);
        aQ[s][1] = *(const bf16x8*)(qp + 32 + quad * 8);
    }

    const f32x4 zero = {0.f, 0.f, 0.f, 0.f};
    f32x4 acc[2][4], lac[2];
    #pragma unroll
    for (int s = 0; s < 2; ++s) {
        lac[s] = zero;
        #pragma unroll
        for (int d = 0; d < 4; ++d) acc[s][d] = zero;
    }
    bf16x8 bones;
    #pragma unroll
    for (int j = 0; j < 8; ++j) bones[j] = (short)0x3F80;  // bf16 1.0

    const int srow = lane >> 3;
    const int schk = (lane & 7) ^ (srow & 7);   // swizzled source chunk
    const long kgb = (long)bh * (2048 * 64);
    const long vgb = (long)bh * (64 * 2048);

#define ATTN_STAGE(p_, t_)                                                    \
    _Pragma("unroll")                                                         \
    for (int i2 = 0; i2 < 2; ++i2) {                                          \
        const int i = w * 2 + i2;                                             \
        glds16(KW + kgb + (long)((t_) + i * 8 + srow) * 64 + schk * 8,        \
               &kt[p_][i * 512]);                                             \
        glds16(VW + vgb + (long)(i * 8 + srow) * 2048 + (t_) + schk * 8,      \
               &vt[p_][i * 512]);                                             \
    }

    // Prologue: tiles 0 and 1 in flight (8 outstanding vm ops/wave).
    ATTN_STAGE(0, 0)
    ATTN_STAGE(1, 64)

    const int pos0 = (quad ^ f7) * 8;      // swizzled chunk {quad}
    const int pos1 = pos0 ^ 32;            // swizzled chunk {quad+4}
    u16* pw = ps[w];

    for (int t0 = 0; t0 < 2048; t0 += 64) {
        const int it = t0 >> 6;
        const int p = it % 3;

        // Counted wait: retire current tile's 4 loads; next tile's 4 stay
        // in flight across the barrier (T4). Last iter fully drains.
        if (t0 + 64 < 2048) {
            __asm__ volatile("s_waitcnt vmcnt(4)" ::: "memory");
        } else {
            __asm__ volatile("s_waitcnt vmcnt(0)" ::: "memory");
        }
        __builtin_amdgcn_s_barrier();
        __asm__ volatile("" ::: "memory");
        __builtin_amdgcn_sched_barrier(0);

        // Stage tile i+2 into the buffer last read at iter i-1 (safe: those
        // reads completed before this barrier).
        if (t0 + 128 < 2048) { ATTN_STAGE((it + 2) % 3, t0 + 128) }

        const u16* ktp = kt[p];
        const u16* vtp = vt[p];

        // ---- swapped QK^T: D[t][q]; lane(fr=q,quad): t = sub*16+quad*4+r
        f32x4 sc[2][4];
        __builtin_amdgcn_s_setprio(1);
        #pragma unroll
        for (int s = 0; s < 2; ++s) {
            #pragma unroll
            for (int sub = 0; sub < 4; ++sub) {
                const int row = (sub * 16 + fr) * 64;
                bf16x8 k0 = *(const bf16x8*)&ktp[row + pos0];
                bf16x8 k1 = *(const bf16x8*)&ktp[row + pos1];
                f32x4 z = __builtin_amdgcn_mfma_f32_16x16x32_bf16(k0, aQ[s][0], zero, 0, 0, 0);
                sc[s][sub] = __builtin_amdgcn_mfma_f32_16x16x32_bf16(k1, aQ[s][1], z, 0, 0, 0);
            }
        }
        __builtin_amdgcn_s_setprio(0);

        // ---- exp + packed bf16 convert + vectorized P store (b64) ----
        // q-row = s*16+fr, t = sub*16 + quad*4 + {0..3}
        #pragma unroll
        for (int s = 0; s < 2; ++s) {
            #pragma unroll
            for (int sub = 0; sub < 4; ++sub) {
                float e0 = __expf(sc[s][sub][0]);
                float e1 = __expf(sc[s][sub][1]);
                float e2 = __expf(sc[s][sub][2]);
                float e3 = __expf(sc[s][sub][3]);
                u32 lo, hi;
                asm("v_cvt_pk_bf16_f32 %0, %1, %2" : "=v"(lo) : "v"(e0), "v"(e1));
                asm("v_cvt_pk_bf16_f32 %0, %1, %2" : "=v"(hi) : "v"(e2), "v"(e3));
                uint2 pk2; pk2.x = lo; pk2.y = hi;
                *(uint2*)&pw[(s * 16 + fr) * 72 + sub * 16 + quad * 4] = pk2;
            }
        }
        __asm__ volatile("s_waitcnt lgkmcnt(0)" ::: "memory");

        // ---- l (ones-MFMA) + PV for both q-sets ----
        __builtin_amdgcn_s_setprio(1);
        #pragma unroll
        for (int s = 0; s < 2; ++s) {
            const bf16x8 aP0 = *(const bf16x8*)&pw[(s * 16 + fr) * 72 + quad * 8];
            const bf16x8 aP1 = *(const bf16x8*)&pw[(s * 16 + fr) * 72 + 32 + quad * 8];
            lac[s] = __builtin_amdgcn_mfma_f32_16x16x32_bf16(aP0, bones, lac[s], 0, 0, 0);
            lac[s] = __builtin_amdgcn_mfma_f32_16x16x32_bf16(aP1, bones, lac[s], 0, 0, 0);
            #pragma unroll
            for (int d = 0; d < 4; ++d) {
                const int row = (d * 16 + fr) * 64;
                bf16x8 v0 = *(const bf16x8*)&vtp[row + pos0];
                bf16x8 v1 = *(const bf16x8*)&vtp[row + pos1];
                acc[s][d] = __builtin_amdgcn_mfma_f32_16x16x32_bf16(aP0, v0, acc[s][d], 0, 0, 0);
                acc[s][d] = __builtin_amdgcn_mfma_f32_16x16x32_bf16(aP1, v1, acc[s][d], 0, 0, 0);
            }
        }
        __builtin_amdgcn_s_setprio(0);
        // no trailing barrier: next iter's counted-wait + barrier covers it
    }

    // epilogue: ctx = acc/(l*128), row = q0 + w*32 + s*16 + quad*4 + r
    #pragma unroll
    for (int s = 0; s < 2; ++s) {
        #pragma unroll
        for (int r = 0; r < 4; ++r) {
            const float scl = 1.0f / (lac[s][r] * 128.0f);
            const long row = (long)b * 2048 + q0 + w * 32 + s * 16 + quad * 4 + r;
            #pragma unroll
            for (int d = 0; d < 4; ++d)
                ctxb[row * 1024 + h * 64 + d * 16 + fr] = f2b(acc[s][d][r] * scl);
        }
    }
}

// ---------------------------------------------------------------------------
extern "C" void kernel_launch(void* const* d_in, const int* in_sizes, int n_in,
                              void* d_out, int out_size, void* d_ws, size_t ws_size,
                              hipStream_t stream) {
    (void)in_sizes; (void)n_in; (void)out_size; (void)ws_size;

    const float* Q  = (const float*)d_in[0];
    const float* K  = (const float*)d_in[1];
    const float* V  = (const float*)d_in[2];
    const float* Wq = (const float*)d_in[3];
    const float* bq = (const float*)d_in[4];
    const float* Wk = (const float*)d_in[5];
    const float* bk = (const float*)d_in[6];
    const float* Wv = (const float*)d_in[7];
    const float* bv = (const float*)d_in[8];
    const float* Wo = (const float*)d_in[9];
    const float* bo = (const float*)d_in[10];
    float* out = (float*)d_out;

    u16* ws  = (u16*)d_ws;                // 64 MB total
    u16* Qb  = ws;                        // 4096x1024
    u16* Kb  = Qb  + 4194304;
    u16* Vb  = Kb  + 4194304;
    u16* WqT = Vb  + 4194304;             // [16][64][1024]
    u16* WkT = WqT + 1048576;
    u16* WvT = WkT + 1048576;
    u16* WoT = WvT + 1048576;             // [1024][1024]
    u16* QWb = WoT + 1048576;             // [32][2048][64]
    u16* KWb = QWb + 4194304;             // [32][2048][64]
    u16* VWb = KWb + 4194304;             // [32][64][2048]
    u16* ctx = VWb + 4194304;             // [4096][1024]

    prep<<<dim3(1024, 1, 5), 256, 0, stream>>>(Q, K, V, Wq, Wk, Wv, Wo,
                                               Qb, Kb, Vb, WqT, WkT, WvT, WoT);

    // grid: x = m-tile (32), y = n-tile (8) for XCD L2 locality
    proj3<<<dim3(32, 8, 3), 256, 0, stream>>>(Qb, Kb, Vb, WqT, WkT, WvT,
                                              bq, bk, bv, QWb, KWb, VWb);

    attn_mfma<<<dim3(16, 32), 256, 0, stream>>>(QWb, KWb, VWb, ctx);

    gemm_out<<<dim3(32, 8), 256, 0, stream>>>(ctx, WoT, bo, out);
}

// Round 11
// 218.892 us; speedup vs baseline: 1.0897x; 1.0206x over previous
//
#include <hip/hip_runtime.h>

typedef unsigned short u16;
typedef unsigned int u32;
typedef __attribute__((ext_vector_type(8))) short bf16x8;
typedef __attribute__((ext_vector_type(4))) float f32x4;

__device__ __forceinline__ u16 f2b(float f) {
    union { float f; u32 u; } v; v.f = f;
    return (u16)((v.u + 0x7FFF + ((v.u >> 16) & 1)) >> 16);  // RNE
}

__device__ __forceinline__ void glds16(const u16* g, u16* l) {
    __builtin_amdgcn_global_load_lds(
        (const __attribute__((address_space(1))) void*)g,
        (__attribute__((address_space(3))) void*)l, 16, 0, 0);
}

// ---------------------------------------------------------------------------
// Fused prep: grid (1024, 1, 5).
//   z<3 : fp32 -> bf16 flat cast of Q/K/V (n4 = 1048576 float4's each).
//   z==3: per-head weight transpose-cast fp32 [16][1024][64] -> [16][64][1024]
//         (x<768: r0i = x&15, sel = x>>8, hz = (x>>4)&15).
//   z==4: Wo transpose-cast fp32 [1024][1024] -> ^T (x<256).
// NOTE: harness INPUTS are cast to bf16 UNMODIFIED (reference quantizes the
// raw inputs — any pre-scale here breaks cancellation). The log2(e) fold for
// exp2 happens in proj3's fp32 epilogue on OUR intermediate, which is safe:
// r6-vs-r5 evidence shows the prescale was innocent (ps-relayout was the bug).
// ---------------------------------------------------------------------------
__global__ __launch_bounds__(256) void prep(
    const float* __restrict__ Q, const float* __restrict__ K,
    const float* __restrict__ V,
    const float* __restrict__ Wq, const float* __restrict__ Wk,
    const float* __restrict__ Wv, const float* __restrict__ Wo,
    u16* __restrict__ Qb, u16* __restrict__ Kb, u16* __restrict__ Vb,
    u16* __restrict__ WqT, u16* __restrict__ WkT, u16* __restrict__ WvT,
    u16* __restrict__ WoT)
{
    __shared__ float t[64][68];
    const int z = blockIdx.z, x = blockIdx.x, tid = threadIdx.x;

    if (z < 3) {
        const float* in = (z == 0) ? Q : (z == 1) ? K : V;
        u16* out = (z == 0) ? Qb : (z == 1) ? Kb : Vb;
        const int n4 = 1048576;
        const int stride = 1024 * 256;
        for (int i = x * 256 + tid; i < n4; i += stride) {
            float4 v = ((const float4*)in)[i];
            ushort4 o;
            o.x = f2b(v.x); o.y = f2b(v.y); o.z = f2b(v.z); o.w = f2b(v.w);
            ((ushort4*)out)[i] = o;
        }
        return;
    }

    const int rr = tid >> 4, c4 = (tid & 15) * 4;

    if (z == 3) {
        if (x >= 768) return;
        const int sel = x >> 8, hz = (x >> 4) & 15;
        const float* in = (sel == 0) ? Wq : (sel == 1) ? Wk : Wv;
        u16* out = (sel == 0) ? WqT : (sel == 1) ? WkT : WvT;
        const long mb = (long)hz * 65536;
        const int r0 = (x & 15) * 64;

        #pragma unroll
        for (int p = 0; p < 4; ++p) {
            float4 v = *(const float4*)(in + mb + (long)(r0 + p * 16 + rr) * 64 + c4);
            *(float4*)&t[p * 16 + rr][c4] = v;
        }
        __syncthreads();
        #pragma unroll
        for (int p = 0; p < 4; ++p) {
            const int oc = p * 16 + rr;
            const int r4 = (tid & 15) * 4;
            ushort4 o;
            o.x = f2b(t[r4 + 0][oc]); o.y = f2b(t[r4 + 1][oc]);
            o.z = f2b(t[r4 + 2][oc]); o.w = f2b(t[r4 + 3][oc]);
            *(ushort4*)(out + mb + (long)oc * 1024 + r0 + r4) = o;
        }
        return;
    }

    // z == 4: Wo
    if (x >= 256) return;
    const int r0 = (x & 15) * 64, c0 = (x >> 4) * 64;
    #pragma unroll
    for (int p = 0; p < 4; ++p) {
        float4 v = *(const float4*)(Wo + (long)(r0 + p * 16 + rr) * 1024 + c0 + c4);
        *(float4*)&t[p * 16 + rr][c4] = v;
    }
    __syncthreads();
    #pragma unroll
    for (int p = 0; p < 4; ++p) {
        const int oc = p * 16 + rr;
        const int r4 = (tid & 15) * 4;
        ushort4 o;
        o.x = f2b(t[r4 + 0][oc]); o.y = f2b(t[r4 + 1][oc]);
        o.z = f2b(t[r4 + 2][oc]); o.w = f2b(t[r4 + 3][oc]);
        *(ushort4*)(WoT + (long)(c0 + oc) * 1024 + r0 + r4) = o;
    }
}

// ---------------------------------------------------------------------------
// GEMM body shared by proj3 / gemm_out — round-8 proven version (BK=64,
// 128x128 tile, 4 waves 2x2, XOR-swizzled LDS chunk^(row&7) — the ONLY
// hardware-validated zero-conflict swizzle, r2 measurement).
// Double-buffered prefetch, single barrier per K-step, s_setprio around MFMA.
// Grid mapping: x = m-tile (32), y = n-tile (8) for XCD L2 locality.
// (r9 lesson: BK=32 + mod-4 swizzle regressed — 3.1M conflicts + halved
//  MFMA-per-barrier amortization. Do not re-attempt paper-only swizzles.)
// ---------------------------------------------------------------------------
#define GEMM_STAGE(A_, BT_, p_, k_)                                            \
    _Pragma("unroll")                                                          \
    for (int i2 = 0; i2 < 4; ++i2) {                                           \
        const int i = w * 4 + i2;                                              \
        glds16(A_ + ga + (long)i * 8 * 1024 + (k_), &As[p_][i * 512]);         \
        glds16(BT_ + gb + (long)i * 8 * 1024 + (k_), &Bs[p_][i * 512]);        \
    }

#define GEMM_CORE(A_, BT_)                                                     \
    __shared__ u16 As[2][128 * 64];                                            \
    __shared__ u16 Bs[2][128 * 64];                                            \
    const int tid = threadIdx.x, lane = tid & 63, w = tid >> 6;                \
    const int m0 = blockIdx.x * 128, n0 = blockIdx.y * 128;                    \
    const int wm = (w >> 1) * 64, wn = (w & 1) * 64;                           \
    const int fr = lane & 15, quad = lane >> 4;                                \
    f32x4 acc[4][4];                                                           \
    const f32x4 zero = {0.f, 0.f, 0.f, 0.f};                                   \
    _Pragma("unroll")                                                          \
    for (int mi = 0; mi < 4; ++mi)                                             \
        _Pragma("unroll")                                                      \
        for (int ni = 0; ni < 4; ++ni) acc[mi][ni] = zero;                     \
    const int srow = lane >> 3;                                                \
    const int schk = (lane & 7) ^ (srow & 7);   /* swizzled source chunk */    \
    const long ga = (long)(m0 + srow) * 1024 + schk * 8;                       \
    const long gb = (long)(n0 + srow) * 1024 + schk * 8;                       \
    const int f7 = fr & 7;                                                     \
    GEMM_STAGE(A_, BT_, 0, 0)                                                  \
    __syncthreads();                                                           \
    for (int k0 = 0; k0 < 1024; k0 += 64) {                                    \
        const int p = (k0 >> 6) & 1;                                           \
        if (k0 + 64 < 1024) { GEMM_STAGE(A_, BT_, p ^ 1, k0 + 64) }            \
        __builtin_amdgcn_s_setprio(1);                                         \
        _Pragma("unroll")                                                      \
        for (int kc = 0; kc < 2; ++kc) {                                       \
            const int pos = ((kc * 4 + quad) ^ f7) * 8;                        \
            bf16x8 af[4], bfr[4];                                              \
            _Pragma("unroll")                                                  \
            for (int mi = 0; mi < 4; ++mi)                                     \
                af[mi] = *(const bf16x8*)&As[p][(wm + mi * 16 + fr) * 64 + pos]; \
            _Pragma("unroll")                                                  \
            for (int ni = 0; ni < 4; ++ni)                                     \
                bfr[ni] = *(const bf16x8*)&Bs[p][(wn + ni * 16 + fr) * 64 + pos]; \
            _Pragma("unroll")                                                  \
            for (int mi = 0; mi < 4; ++mi)                                     \
                _Pragma("unroll")                                              \
                for (int ni = 0; ni < 4; ++ni)                                 \
                    acc[mi][ni] = __builtin_amdgcn_mfma_f32_16x16x32_bf16(     \
                        af[mi], bfr[ni], acc[mi][ni], 0, 0, 0);                \
        }                                                                      \
        __builtin_amdgcn_s_setprio(0);                                         \
        __syncthreads();                                                       \
    }

// Projections (z: 0=Q, 1=K, 2=V). OUT: z<2 -> [bh][s][64]; z==2 -> [bh][64][s]
// z==0 is scaled by log2(e) in fp32 BEFORE our bf16 intermediate cast so
// attention can use raw v_exp_f32 (exp2). Error-neutral: noise and signal
// scale together, and d/ds[exp2(log2e*s)] == d/ds[exp(s)].
__global__ __launch_bounds__(256) void proj3(
    const u16* __restrict__ Qb, const u16* __restrict__ Kb,
    const u16* __restrict__ Vb,
    const u16* __restrict__ WqT, const u16* __restrict__ WkT,
    const u16* __restrict__ WvT,
    const float* __restrict__ bq, const float* __restrict__ bk,
    const float* __restrict__ bv,
    u16* __restrict__ QWb, u16* __restrict__ KWb, u16* __restrict__ VWb)
{
    const int z = blockIdx.z;
    const u16* A  = (z == 0) ? Qb : (z == 1) ? Kb : Vb;
    const u16* BT = (z == 0) ? WqT : (z == 1) ? WkT : WvT;
    const float* bias = (z == 0) ? bq : (z == 1) ? bk : bv;
    u16* Cu = (z == 0) ? QWb : (z == 1) ? KWb : VWb;
    const float scl = (z == 0) ? 1.4426950408889634f : 1.0f;  // log2(e) for Q

    GEMM_CORE(A, BT)

    #pragma unroll
    for (int mi = 0; mi < 4; ++mi) {
        #pragma unroll
        for (int ni = 0; ni < 4; ++ni) {
            const int mB = m0 + wm + mi * 16 + quad * 4;   // r = 0 row
            const int c  = n0 + wn + ni * 16 + fr;
            const int b = mB >> 11, s = mB & 2047, h = c >> 6, k = c & 63;
            const float bi = bias[c];
            if (z != 2) {
                #pragma unroll
                for (int r = 0; r < 4; ++r)
                    Cu[((long)(b * 16 + h) * 2048 + s + r) * 64 + k] =
                        f2b((acc[mi][ni][r] + bi) * scl);
            } else {
                ushort4 o;
                o.x = f2b(acc[mi][ni][0] + bi);
                o.y = f2b(acc[mi][ni][1] + bi);
                o.z = f2b(acc[mi][ni][2] + bi);
                o.w = f2b(acc[mi][ni][3] + bi);
                *(ushort4*)&Cu[((long)(b * 16 + h) * 64 + k) * 2048 + s] = o;
            }
        }
    }
}

// Output projection: fp32 out = ctx(bf16) @ WoT^T + bo
__global__ __launch_bounds__(256) void gemm_out(
    const u16* __restrict__ A, const u16* __restrict__ BT,
    const float* __restrict__ bias, float* __restrict__ Cf)
{
    GEMM_CORE(A, BT)

    #pragma unroll
    for (int mi = 0; mi < 4; ++mi) {
        #pragma unroll
        for (int ni = 0; ni < 4; ++ni) {
            #pragma unroll
            for (int r = 0; r < 4; ++r) {
                const int m = m0 + wm + mi * 16 + quad * 4 + r;
                const int c = n0 + wn + ni * 16 + fr;
                Cf[(long)m * 1024 + c] = acc[mi][ni][r] + bias[c];
            }
        }
    }
}

// ---------------------------------------------------------------------------
// MFMA flash attention — round-8 structure; exp via raw v_exp_f32 (exp2),
// QW pre-scaled by log2(e) in proj3's fp32 epilogue.
//   QW/KW: [bh][2048][64]; VW: [bh][64][2048] (bf16).
//   Block = 4 waves, 128 q rows (32 per wave as 2 sets of 16).
//   Distance-2 prefetch over 3 LDS buffers, counted vmcnt(4) + raw s_barrier.
//   XCD colocate remap: id%8 = XCD; 4 heads x 16 q-tiles per XCD.
//   ps is LINEAR stride-72 (XOR relayout failed on HW in r5/r6 — burned).
//   Swapped QK^T (mfma(K,Q) -> t-consecutive regs -> cvt_pk + b64 P store),
//   s_setprio around MFMA clusters. Non-centered softmax, l via ones-MFMA;
//   ctx scaled by 1/(l*128).
// ---------------------------------------------------------------------------
__global__ __launch_bounds__(256) void attn_mfma(
    const u16* __restrict__ QW, const u16* __restrict__ KW,
    const u16* __restrict__ VW, u16* __restrict__ ctxb)
{
    __shared__ u16 kt[3][64 * 64];   // [buf][t][k] swizzled, 24 KB
    __shared__ u16 vt[3][64 * 64];   // [buf][d][t] swizzled, 24 KB
    __shared__ u16 ps[4][32 * 72];   // per-wave P [q][t], stride 72, 18 KB

    const int tid = threadIdx.x, lane = tid & 63, w = tid >> 6;
    // XCD colocate: id%8 is the XCD (round-robin dispatch). Bijection:
    // bh = (id&7)*4 + ((id>>3)&3), qt = id>>5  (512 blocks total).
    const int id = blockIdx.x + gridDim.x * blockIdx.y;
    const int bh = (id & 7) * 4 + ((id >> 3) & 3);
    const int q0 = (id >> 5) * 128;
    const int b = bh >> 4, h = bh & 15;
    const int fr = lane & 15, quad = lane >> 4;
    const int f7 = fr & 7;

    // Q fragments (B-operand of swapped QK^T): 2 q-sets of 16 rows, q = fr
    bf16x8 aQ[2][2];
    #pragma unroll
    for (int s = 0; s < 2; ++s) {
        const u16* qp = QW + ((long)bh * 2048 + q0 + w * 32 + s * 16 + fr) * 64;
        aQ[s][0] = *(const bf16x8*)(qp + quad * 8);
        aQ[s][1] = *(const bf16x8*)(qp + 32 + quad * 8);
    }

    const f32x4 zero = {0.f, 0.f, 0.f, 0.f};
    f32x4 acc[2][4], lac[2];
    #pragma unroll
    for (int s = 0; s < 2; ++s) {
        lac[s] = zero;
        #pragma unroll
        for (int d = 0; d < 4; ++d) acc[s][d] = zero;
    }
    bf16x8 bones;
    #pragma unroll
    for (int j = 0; j < 8; ++j) bones[j] = (short)0x3F80;  // bf16 1.0

    const int srow = lane >> 3;
    const int schk = (lane & 7) ^ (srow & 7);   // swizzled source chunk
    const long kgb = (long)bh * (2048 * 64);
    const long vgb = (long)bh * (64 * 2048);

#define ATTN_STAGE(p_, t_)                                                    \
    _Pragma("unroll")                                                         \
    for (int i2 = 0; i2 < 2; ++i2) {                                          \
        const int i = w * 2 + i2;                                             \
        glds16(KW + kgb + (long)((t_) + i * 8 + srow) * 64 + schk * 8,        \
               &kt[p_][i * 512]);                                             \
        glds16(VW + vgb + (long)(i * 8 + srow) * 2048 + (t_) + schk * 8,      \
               &vt[p_][i * 512]);                                             \
    }

    // Prologue: tiles 0 and 1 in flight (8 outstanding vm ops/wave).
    ATTN_STAGE(0, 0)
    ATTN_STAGE(1, 64)

    const int pos0 = (quad ^ f7) * 8;      // swizzled chunk {quad}
    const int pos1 = pos0 ^ 32;            // swizzled chunk {quad+4}
    u16* pw = ps[w];

    for (int t0 = 0; t0 < 2048; t0 += 64) {
        const int it = t0 >> 6;
        const int p = it % 3;

        // Counted wait: retire current tile's 4 loads; next tile's 4 stay
        // in flight across the barrier (T4). Last iter fully drains.
        if (t0 + 64 < 2048) {
            __asm__ volatile("s_waitcnt vmcnt(4)" ::: "memory");
        } else {
            __asm__ volatile("s_waitcnt vmcnt(0)" ::: "memory");
        }
        __builtin_amdgcn_s_barrier();
        __asm__ volatile("" ::: "memory");
        __builtin_amdgcn_sched_barrier(0);

        // Stage tile i+2 into the buffer last read at iter i-1 (safe: those
        // reads completed before this barrier).
        if (t0 + 128 < 2048) { ATTN_STAGE((it + 2) % 3, t0 + 128) }

        const u16* ktp = kt[p];
        const u16* vtp = vt[p];

        // ---- swapped QK^T: D[t][q]; lane(fr=q,quad): t = sub*16+quad*4+r
        f32x4 sc[2][4];
        __builtin_amdgcn_s_setprio(1);
        #pragma unroll
        for (int s = 0; s < 2; ++s) {
            #pragma unroll
            for (int sub = 0; sub < 4; ++sub) {
                const int row = (sub * 16 + fr) * 64;
                bf16x8 k0 = *(const bf16x8*)&ktp[row + pos0];
                bf16x8 k1 = *(const bf16x8*)&ktp[row + pos1];
                f32x4 z = __builtin_amdgcn_mfma_f32_16x16x32_bf16(k0, aQ[s][0], zero, 0, 0, 0);
                sc[s][sub] = __builtin_amdgcn_mfma_f32_16x16x32_bf16(k1, aQ[s][1], z, 0, 0, 0);
            }
        }
        __builtin_amdgcn_s_setprio(0);

        // ---- exp2 + packed bf16 convert + vectorized P store (b64) ----
        // q-row = s*16+fr, t = sub*16 + quad*4 + {0..3}
        #pragma unroll
        for (int s = 0; s < 2; ++s) {
            #pragma unroll
            for (int sub = 0; sub < 4; ++sub) {
                float e0 = __builtin_amdgcn_exp2f(sc[s][sub][0]);
                float e1 = __builtin_amdgcn_exp2f(sc[s][sub][1]);
                float e2 = __builtin_amdgcn_exp2f(sc[s][sub][2]);
                float e3 = __builtin_amdgcn_exp2f(sc[s][sub][3]);
                u32 lo, hi;
                asm("v_cvt_pk_bf16_f32 %0, %1, %2" : "=v"(lo) : "v"(e0), "v"(e1));
                asm("v_cvt_pk_bf16_f32 %0, %1, %2" : "=v"(hi) : "v"(e2), "v"(e3));
                uint2 pk2; pk2.x = lo; pk2.y = hi;
                *(uint2*)&pw[(s * 16 + fr) * 72 + sub * 16 + quad * 4] = pk2;
            }
        }
        __asm__ volatile("s_waitcnt lgkmcnt(0)" ::: "memory");

        // ---- l (ones-MFMA) + PV for both q-sets ----
        __builtin_amdgcn_s_setprio(1);
        #pragma unroll
        for (int s = 0; s < 2; ++s) {
            const bf16x8 aP0 = *(const bf16x8*)&pw[(s * 16 + fr) * 72 + quad * 8];
            const bf16x8 aP1 = *(const bf16x8*)&pw[(s * 16 + fr) * 72 + 32 + quad * 8];
            lac[s] = __builtin_amdgcn_mfma_f32_16x16x32_bf16(aP0, bones, lac[s], 0, 0, 0);
            lac[s] = __builtin_amdgcn_mfma_f32_16x16x32_bf16(aP1, bones, lac[s], 0, 0, 0);
            #pragma unroll
            for (int d = 0; d < 4; ++d) {
                const int row = (d * 16 + fr) * 64;
                bf16x8 v0 = *(const bf16x8*)&vtp[row + pos0];
                bf16x8 v1 = *(const bf16x8*)&vtp[row + pos1];
                acc[s][d] = __builtin_amdgcn_mfma_f32_16x16x32_bf16(aP0, v0, acc[s][d], 0, 0, 0);
                acc[s][d] = __builtin_amdgcn_mfma_f32_16x16x32_bf16(aP1, v1, acc[s][d], 0, 0, 0);
            }
        }
        __builtin_amdgcn_s_setprio(0);
        // no trailing barrier: next iter's counted-wait + barrier covers it
    }

    // epilogue: ctx = acc/(l*128), row = q0 + w*32 + s*16 + quad*4 + r
    #pragma unroll
    for (int s = 0; s < 2; ++s) {
        #pragma unroll
        for (int r = 0; r < 4; ++r) {
            const float scl = 1.0f / (lac[s][r] * 128.0f);
            const long row = (long)b * 2048 + q0 + w * 32 + s * 16 + quad * 4 + r;
            #pragma unroll
            for (int d = 0; d < 4; ++d)
                ctxb[row * 1024 + h * 64 + d * 16 + fr] = f2b(acc[s][d][r] * scl);
        }
    }
}

// ---------------------------------------------------------------------------
extern "C" void kernel_launch(void* const* d_in, const int* in_sizes, int n_in,
                              void* d_out, int out_size, void* d_ws, size_t ws_size,
                              hipStream_t stream) {
    (void)in_sizes; (void)n_in; (void)out_size; (void)ws_size;

    const float* Q  = (const float*)d_in[0];
    const float* K  = (const float*)d_in[1];
    const float* V  = (const float*)d_in[2];
    const float* Wq = (const float*)d_in[3];
    const float* bq = (const float*)d_in[4];
    const float* Wk = (const float*)d_in[5];
    const float* bk = (const float*)d_in[6];
    const float* Wv = (const float*)d_in[7];
    const float* bv = (const float*)d_in[8];
    const float* Wo = (const float*)d_in[9];
    const float* bo = (const float*)d_in[10];
    float* out = (float*)d_out;

    u16* ws  = (u16*)d_ws;                // 64 MB total
    u16* Qb  = ws;                        // 4096x1024
    u16* Kb  = Qb  + 4194304;
    u16* Vb  = Kb  + 4194304;
    u16* WqT = Vb  + 4194304;             // [16][64][1024]
    u16* WkT = WqT + 1048576;
    u16* WvT = WkT + 1048576;
    u16* WoT = WvT + 1048576;             // [1024][1024]
    u16* QWb = WoT + 1048576;             // [32][2048][64]
    u16* KWb = QWb + 4194304;             // [32][2048][64]
    u16* VWb = KWb + 4194304;             // [32][64][2048]
    u16* ctx = VWb + 4194304;             // [4096][1024]

    prep<<<dim3(1024, 1, 5), 256, 0, stream>>>(Q, K, V, Wq, Wk, Wv, Wo,
                                               Qb, Kb, Vb, WqT, WkT, WvT, WoT);

    // grid: x = m-tile (32), y = n-tile (8) for XCD L2 locality
    proj3<<<dim3(32, 8, 3), 256, 0, stream>>>(Qb, Kb, Vb, WqT, WkT, WvT,
                                              bq, bk, bv, QWb, KWb, VWb);

    attn_mfma<<<dim3(16, 32), 256, 0, stream>>>(QWb, KWb, VWb, ctx);

    gemm_out<<<dim3(32, 8), 256, 0, stream>>>(ctx, WoT, bo, out);
}

// Round 12
// 218.741 us; speedup vs baseline: 1.0905x; 1.0007x over previous
//
#include <hip/hip_runtime.h>

typedef unsigned short u16;
typedef unsigned int u32;
typedef __attribute__((ext_vector_type(8))) short bf16x8;
typedef __attribute__((ext_vector_type(4))) float f32x4;

__device__ __forceinline__ u16 f2b(float f) {
    union { float f; u32 u; } v; v.f = f;
    return (u16)((v.u + 0x7FFF + ((v.u >> 16) & 1)) >> 16);  // RNE
}

__device__ __forceinline__ void glds16(const u16* g, u16* l) {
    __builtin_amdgcn_global_load_lds(
        (const __attribute__((address_space(1))) void*)g,
        (__attribute__((address_space(3))) void*)l, 16, 0, 0);
}

// ---------------------------------------------------------------------------
// Fused prep: grid (1024, 1, 5).
//   z<3 : fp32 -> bf16 flat cast of Q/K/V (n4 = 1048576 float4's each).
//   z==3: per-head weight transpose-cast fp32 [16][1024][64] -> [16][64][1024]
//   z==4: Wo transpose-cast fp32 [1024][1024] -> ^T (x<256).
// Harness INPUTS are cast to bf16 UNMODIFIED (reference quantizes the raw
// inputs). log2(e) fold happens in proj3's fp32 epilogue (r11-proven safe).
// ---------------------------------------------------------------------------
__global__ __launch_bounds__(256) void prep(
    const float* __restrict__ Q, const float* __restrict__ K,
    const float* __restrict__ V,
    const float* __restrict__ Wq, const float* __restrict__ Wk,
    const float* __restrict__ Wv, const float* __restrict__ Wo,
    u16* __restrict__ Qb, u16* __restrict__ Kb, u16* __restrict__ Vb,
    u16* __restrict__ WqT, u16* __restrict__ WkT, u16* __restrict__ WvT,
    u16* __restrict__ WoT)
{
    __shared__ float t[64][68];
    const int z = blockIdx.z, x = blockIdx.x, tid = threadIdx.x;

    if (z < 3) {
        const float* in = (z == 0) ? Q : (z == 1) ? K : V;
        u16* out = (z == 0) ? Qb : (z == 1) ? Kb : Vb;
        const int n4 = 1048576;
        const int stride = 1024 * 256;
        for (int i = x * 256 + tid; i < n4; i += stride) {
            float4 v = ((const float4*)in)[i];
            ushort4 o;
            o.x = f2b(v.x); o.y = f2b(v.y); o.z = f2b(v.z); o.w = f2b(v.w);
            ((ushort4*)out)[i] = o;
        }
        return;
    }

    const int rr = tid >> 4, c4 = (tid & 15) * 4;

    if (z == 3) {
        if (x >= 768) return;
        const int sel = x >> 8, hz = (x >> 4) & 15;
        const float* in = (sel == 0) ? Wq : (sel == 1) ? Wk : Wv;
        u16* out = (sel == 0) ? WqT : (sel == 1) ? WkT : WvT;
        const long mb = (long)hz * 65536;
        const int r0 = (x & 15) * 64;

        #pragma unroll
        for (int p = 0; p < 4; ++p) {
            float4 v = *(const float4*)(in + mb + (long)(r0 + p * 16 + rr) * 64 + c4);
            *(float4*)&t[p * 16 + rr][c4] = v;
        }
        __syncthreads();
        #pragma unroll
        for (int p = 0; p < 4; ++p) {
            const int oc = p * 16 + rr;
            const int r4 = (tid & 15) * 4;
            ushort4 o;
            o.x = f2b(t[r4 + 0][oc]); o.y = f2b(t[r4 + 1][oc]);
            o.z = f2b(t[r4 + 2][oc]); o.w = f2b(t[r4 + 3][oc]);
            *(ushort4*)(out + mb + (long)oc * 1024 + r0 + r4) = o;
        }
        return;
    }

    // z == 4: Wo
    if (x >= 256) return;
    const int r0 = (x & 15) * 64, c0 = (x >> 4) * 64;
    #pragma unroll
    for (int p = 0; p < 4; ++p) {
        float4 v = *(const float4*)(Wo + (long)(r0 + p * 16 + rr) * 1024 + c0 + c4);
        *(float4*)&t[p * 16 + rr][c4] = v;
    }
    __syncthreads();
    #pragma unroll
    for (int p = 0; p < 4; ++p) {
        const int oc = p * 16 + rr;
        const int r4 = (tid & 15) * 4;
        ushort4 o;
        o.x = f2b(t[r4 + 0][oc]); o.y = f2b(t[r4 + 1][oc]);
        o.z = f2b(t[r4 + 2][oc]); o.w = f2b(t[r4 + 3][oc]);
        *(ushort4*)(WoT + (long)(c0 + oc) * 1024 + r0 + r4) = o;
    }
}

// ---------------------------------------------------------------------------
// proj3 GEMM body — SINGLE-buffered (r2-proven core: 0 bank conflicts on HW),
// 128x128 tile, 4 waves 2x2, XOR-swizzled LDS chunk^(row&7), BK=64.
// 32 KB LDS -> 3 blocks/CU -> ALL 768 blocks resident (vs dbuf's 2/CU):
// inter-block overlap hides the per-K-step barrier drain (m97: this config
// is the 874 TF one; m99/m100: explicit dbuf adds nothing at equal occupancy).
// Grid (32,8,3): x = m-tile for XCD L2 locality (r3-proven). setprio r3-proven.
// ---------------------------------------------------------------------------
#define GEMM_STAGE_SB(A_, BT_, k_)                                             \
    _Pragma("unroll")                                                          \
    for (int i2 = 0; i2 < 4; ++i2) {                                           \
        const int i = w * 4 + i2;                                              \
        glds16(A_ + ga + (long)i * 8 * 1024 + (k_), &As[i * 512]);             \
        glds16(BT_ + gb + (long)i * 8 * 1024 + (k_), &Bs[i * 512]);            \
    }

#define GEMM_CORE_SB(A_, BT_)                                                  \
    __shared__ u16 As[128 * 64];                                               \
    __shared__ u16 Bs[128 * 64];                                               \
    const int tid = threadIdx.x, lane = tid & 63, w = tid >> 6;                \
    const int m0 = blockIdx.x * 128, n0 = blockIdx.y * 128;                    \
    const int wm = (w >> 1) * 64, wn = (w & 1) * 64;                           \
    const int fr = lane & 15, quad = lane >> 4;                                \
    f32x4 acc[4][4];                                                           \
    const f32x4 zero = {0.f, 0.f, 0.f, 0.f};                                   \
    _Pragma("unroll")                                                          \
    for (int mi = 0; mi < 4; ++mi)                                             \
        _Pragma("unroll")                                                      \
        for (int ni = 0; ni < 4; ++ni) acc[mi][ni] = zero;                     \
    const int srow = lane >> 3;                                                \
    const int schk = (lane & 7) ^ (srow & 7);   /* swizzled source chunk */    \
    const long ga = (long)(m0 + srow) * 1024 + schk * 8;                       \
    const long gb = (long)(n0 + srow) * 1024 + schk * 8;                       \
    const int f7 = fr & 7;                                                     \
    for (int k0 = 0; k0 < 1024; k0 += 64) {                                    \
        __syncthreads();                                                       \
        GEMM_STAGE_SB(A_, BT_, k0)                                             \
        __syncthreads();                                                       \
        __builtin_amdgcn_s_setprio(1);                                         \
        _Pragma("unroll")                                                      \
        for (int kc = 0; kc < 2; ++kc) {                                       \
            const int pos = ((kc * 4 + quad) ^ f7) * 8;                        \
            bf16x8 af[4], bfr[4];                                              \
            _Pragma("unroll")                                                  \
            for (int mi = 0; mi < 4; ++mi)                                     \
                af[mi] = *(const bf16x8*)&As[(wm + mi * 16 + fr) * 64 + pos];  \
            _Pragma("unroll")                                                  \
            for (int ni = 0; ni < 4; ++ni)                                     \
                bfr[ni] = *(const bf16x8*)&Bs[(wn + ni * 16 + fr) * 64 + pos]; \
            _Pragma("unroll")                                                  \
            for (int mi = 0; mi < 4; ++mi)                                     \
                _Pragma("unroll")                                              \
                for (int ni = 0; ni < 4; ++ni)                                 \
                    acc[mi][ni] = __builtin_amdgcn_mfma_f32_16x16x32_bf16(     \
                        af[mi], bfr[ni], acc[mi][ni], 0, 0, 0);                \
        }                                                                      \
        __builtin_amdgcn_s_setprio(0);                                         \
    }

// Projections (z: 0=Q, 1=K, 2=V). OUT: z<2 -> [bh][s][64]; z==2 -> [bh][64][s]
// z==0 scaled by log2(e) in fp32 before the bf16 intermediate cast (r11-proven)
__global__ __launch_bounds__(256) void proj3(
    const u16* __restrict__ Qb, const u16* __restrict__ Kb,
    const u16* __restrict__ Vb,
    const u16* __restrict__ WqT, const u16* __restrict__ WkT,
    const u16* __restrict__ WvT,
    const float* __restrict__ bq, const float* __restrict__ bk,
    const float* __restrict__ bv,
    u16* __restrict__ QWb, u16* __restrict__ KWb, u16* __restrict__ VWb)
{
    const int z = blockIdx.z;
    const u16* A  = (z == 0) ? Qb : (z == 1) ? Kb : Vb;
    const u16* BT = (z == 0) ? WqT : (z == 1) ? WkT : WvT;
    const float* bias = (z == 0) ? bq : (z == 1) ? bk : bv;
    u16* Cu = (z == 0) ? QWb : (z == 1) ? KWb : VWb;
    const float scl = (z == 0) ? 1.4426950408889634f : 1.0f;  // log2(e) for Q

    GEMM_CORE_SB(A, BT)

    #pragma unroll
    for (int mi = 0; mi < 4; ++mi) {
        #pragma unroll
        for (int ni = 0; ni < 4; ++ni) {
            const int mB = m0 + wm + mi * 16 + quad * 4;   // r = 0 row
            const int c  = n0 + wn + ni * 16 + fr;
            const int b = mB >> 11, s = mB & 2047, h = c >> 6, k = c & 63;
            const float bi = bias[c];
            if (z != 2) {
                #pragma unroll
                for (int r = 0; r < 4; ++r)
                    Cu[((long)(b * 16 + h) * 2048 + s + r) * 64 + k] =
                        f2b((acc[mi][ni][r] + bi) * scl);
            } else {
                ushort4 o;
                o.x = f2b(acc[mi][ni][0] + bi);
                o.y = f2b(acc[mi][ni][1] + bi);
                o.z = f2b(acc[mi][ni][2] + bi);
                o.w = f2b(acc[mi][ni][3] + bi);
                *(ushort4*)&Cu[((long)(b * 16 + h) * 64 + k) * 2048 + s] = o;
            }
        }
    }
}

// ---------------------------------------------------------------------------
// Output projection: fp32 out = ctx(bf16) @ WoT^T + bo.
// v2: 128x64 tiles -> grid (32,16) = 512 blocks (was 256 = 1 block/CU, no
// TLP). LDS 24 KB -> 2 blocks/CU resident, all 512 resident. Single-buffered.
// Wave layout: 4 waves 2x2 over (128,64); wave tile 64x32; acc[4][2].
// Same zero-conflict swizzle (read pattern per-row identical to proven core).
// ---------------------------------------------------------------------------
__global__ __launch_bounds__(256) void gemm_out(
    const u16* __restrict__ A, const u16* __restrict__ BT,
    const float* __restrict__ bias, float* __restrict__ Cf)
{
    __shared__ u16 As[128 * 64];   // 16 KB
    __shared__ u16 Bs[64 * 64];    // 8 KB

    const int tid = threadIdx.x, lane = tid & 63, w = tid >> 6;
    const int m0 = blockIdx.x * 128, n0 = blockIdx.y * 64;
    const int wm = (w >> 1) * 64, wn = (w & 1) * 32;
    const int fr = lane & 15, quad = lane >> 4;
    f32x4 acc[4][2];
    const f32x4 zero = {0.f, 0.f, 0.f, 0.f};
    #pragma unroll
    for (int mi = 0; mi < 4; ++mi)
        #pragma unroll
        for (int ni = 0; ni < 2; ++ni) acc[mi][ni] = zero;

    const int srow = lane >> 3;
    const int schk = (lane & 7) ^ (srow & 7);   // swizzled source chunk
    const long ga = (long)(m0 + srow) * 1024 + schk * 8;
    const long gb = (long)(n0 + srow) * 1024 + schk * 8;
    const int f7 = fr & 7;

    for (int k0 = 0; k0 < 1024; k0 += 64) {
        __syncthreads();
        #pragma unroll
        for (int i2 = 0; i2 < 4; ++i2) {          // A: 16 chunks, rows 0..127
            const int i = w * 4 + i2;
            glds16(A + ga + (long)i * 8 * 1024 + k0, &As[i * 512]);
        }
        #pragma unroll
        for (int i2 = 0; i2 < 2; ++i2) {          // B: 8 chunks, rows 0..63
            const int i = w * 2 + i2;
            glds16(BT + gb + (long)i * 8 * 1024 + k0, &Bs[i * 512]);
        }
        __syncthreads();
        __builtin_amdgcn_s_setprio(1);
        #pragma unroll
        for (int kc = 0; kc < 2; ++kc) {
            const int pos = ((kc * 4 + quad) ^ f7) * 8;
            bf16x8 af[4], bfr[2];
            #pragma unroll
            for (int mi = 0; mi < 4; ++mi)
                af[mi] = *(const bf16x8*)&As[(wm + mi * 16 + fr) * 64 + pos];
            #pragma unroll
            for (int ni = 0; ni < 2; ++ni)
                bfr[ni] = *(const bf16x8*)&Bs[(wn + ni * 16 + fr) * 64 + pos];
            #pragma unroll
            for (int mi = 0; mi < 4; ++mi)
                #pragma unroll
                for (int ni = 0; ni < 2; ++ni)
                    acc[mi][ni] = __builtin_amdgcn_mfma_f32_16x16x32_bf16(
                        af[mi], bfr[ni], acc[mi][ni], 0, 0, 0);
        }
        __builtin_amdgcn_s_setprio(0);
    }

    #pragma unroll
    for (int mi = 0; mi < 4; ++mi) {
        #pragma unroll
        for (int ni = 0; ni < 2; ++ni) {
            #pragma unroll
            for (int r = 0; r < 4; ++r) {
                const int m = m0 + wm + mi * 16 + quad * 4 + r;
                const int c = n0 + wn + ni * 16 + fr;
                Cf[(long)m * 1024 + c] = acc[mi][ni][r] + bias[c];
            }
        }
    }
}

// ---------------------------------------------------------------------------
// MFMA flash attention — round-11 passing version (byte-identical).
//   QW (log2e-prescaled)/KW: [bh][2048][64]; VW: [bh][64][2048] (bf16).
//   Block = 4 waves, 128 q rows. Distance-2 prefetch over 3 LDS buffers,
//   counted vmcnt(4) + raw s_barrier. XCD colocate remap. exp via raw
//   v_exp_f32. ps LINEAR stride-72 (XOR relayout HW-failed r5/r6 — burned).
//   Swapped QK^T -> cvt_pk + b64 P store; setprio; l via ones-MFMA;
//   ctx scaled by 1/(l*128).
// ---------------------------------------------------------------------------
__global__ __launch_bounds__(256) void attn_mfma(
    const u16* __restrict__ QW, const u16* __restrict__ KW,
    const u16* __restrict__ VW, u16* __restrict__ ctxb)
{
    __shared__ u16 kt[3][64 * 64];   // [buf][t][k] swizzled, 24 KB
    __shared__ u16 vt[3][64 * 64];   // [buf][d][t] swizzled, 24 KB
    __shared__ u16 ps[4][32 * 72];   // per-wave P [q][t], stride 72, 18 KB

    const int tid = threadIdx.x, lane = tid & 63, w = tid >> 6;
    const int id = blockIdx.x + gridDim.x * blockIdx.y;
    const int bh = (id & 7) * 4 + ((id >> 3) & 3);
    const int q0 = (id >> 5) * 128;
    const int b = bh >> 4, h = bh & 15;
    const int fr = lane & 15, quad = lane >> 4;
    const int f7 = fr & 7;

    bf16x8 aQ[2][2];
    #pragma unroll
    for (int s = 0; s < 2; ++s) {
        const u16* qp = QW + ((long)bh * 2048 + q0 + w * 32 + s * 16 + fr) * 64;
        aQ[s][0] = *(const bf16x8*)(qp + quad * 8);
        aQ[s][1] = *(const bf16x8*)(qp + 32 + quad * 8);
    }

    const f32x4 zero = {0.f, 0.f, 0.f, 0.f};
    f32x4 acc[2][4], lac[2];
    #pragma unroll
    for (int s = 0; s < 2; ++s) {
        lac[s] = zero;
        #pragma unroll
        for (int d = 0; d < 4; ++d) acc[s][d] = zero;
    }
    bf16x8 bones;
    #pragma unroll
    for (int j = 0; j < 8; ++j) bones[j] = (short)0x3F80;  // bf16 1.0

    const int srow = lane >> 3;
    const int schk = (lane & 7) ^ (srow & 7);   // swizzled source chunk
    const long kgb = (long)bh * (2048 * 64);
    const long vgb = (long)bh * (64 * 2048);

#define ATTN_STAGE(p_, t_)                                                    \
    _Pragma("unroll")                                                         \
    for (int i2 = 0; i2 < 2; ++i2) {                                          \
        const int i = w * 2 + i2;                                             \
        glds16(KW + kgb + (long)((t_) + i * 8 + srow) * 64 + schk * 8,        \
               &kt[p_][i * 512]);                                             \
        glds16(VW + vgb + (long)(i * 8 + srow) * 2048 + (t_) + schk * 8,      \
               &vt[p_][i * 512]);                                             \
    }

    ATTN_STAGE(0, 0)
    ATTN_STAGE(1, 64)

    const int pos0 = (quad ^ f7) * 8;      // swizzled chunk {quad}
    const int pos1 = pos0 ^ 32;            // swizzled chunk {quad+4}
    u16* pw = ps[w];

    for (int t0 = 0; t0 < 2048; t0 += 64) {
        const int it = t0 >> 6;
        const int p = it % 3;

        if (t0 + 64 < 2048) {
            __asm__ volatile("s_waitcnt vmcnt(4)" ::: "memory");
        } else {
            __asm__ volatile("s_waitcnt vmcnt(0)" ::: "memory");
        }
        __builtin_amdgcn_s_barrier();
        __asm__ volatile("" ::: "memory");
        __builtin_amdgcn_sched_barrier(0);

        if (t0 + 128 < 2048) { ATTN_STAGE((it + 2) % 3, t0 + 128) }

        const u16* ktp = kt[p];
        const u16* vtp = vt[p];

        // ---- swapped QK^T: D[t][q]; lane(fr=q,quad): t = sub*16+quad*4+r
        f32x4 sc[2][4];
        __builtin_amdgcn_s_setprio(1);
        #pragma unroll
        for (int s = 0; s < 2; ++s) {
            #pragma unroll
            for (int sub = 0; sub < 4; ++sub) {
                const int row = (sub * 16 + fr) * 64;
                bf16x8 k0 = *(const bf16x8*)&ktp[row + pos0];
                bf16x8 k1 = *(const bf16x8*)&ktp[row + pos1];
                f32x4 z = __builtin_amdgcn_mfma_f32_16x16x32_bf16(k0, aQ[s][0], zero, 0, 0, 0);
                sc[s][sub] = __builtin_amdgcn_mfma_f32_16x16x32_bf16(k1, aQ[s][1], z, 0, 0, 0);
            }
        }
        __builtin_amdgcn_s_setprio(0);

        // ---- exp2 + packed bf16 convert + vectorized P store (b64) ----
        #pragma unroll
        for (int s = 0; s < 2; ++s) {
            #pragma unroll
            for (int sub = 0; sub < 4; ++sub) {
                float e0 = __builtin_amdgcn_exp2f(sc[s][sub][0]);
                float e1 = __builtin_amdgcn_exp2f(sc[s][sub][1]);
                float e2 = __builtin_amdgcn_exp2f(sc[s][sub][2]);
                float e3 = __builtin_amdgcn_exp2f(sc[s][sub][3]);
                u32 lo, hi;
                asm("v_cvt_pk_bf16_f32 %0, %1, %2" : "=v"(lo) : "v"(e0), "v"(e1));
                asm("v_cvt_pk_bf16_f32 %0, %1, %2" : "=v"(hi) : "v"(e2), "v"(e3));
                uint2 pk2; pk2.x = lo; pk2.y = hi;
                *(uint2*)&pw[(s * 16 + fr) * 72 + sub * 16 + quad * 4] = pk2;
            }
        }
        __asm__ volatile("s_waitcnt lgkmcnt(0)" ::: "memory");

        // ---- l (ones-MFMA) + PV for both q-sets ----
        __builtin_amdgcn_s_setprio(1);
        #pragma unroll
        for (int s = 0; s < 2; ++s) {
            const bf16x8 aP0 = *(const bf16x8*)&pw[(s * 16 + fr) * 72 + quad * 8];
            const bf16x8 aP1 = *(const bf16x8*)&pw[(s * 16 + fr) * 72 + 32 + quad * 8];
            lac[s] = __builtin_amdgcn_mfma_f32_16x16x32_bf16(aP0, bones, lac[s], 0, 0, 0);
            lac[s] = __builtin_amdgcn_mfma_f32_16x16x32_bf16(aP1, bones, lac[s], 0, 0, 0);
            #pragma unroll
            for (int d = 0; d < 4; ++d) {
                const int row = (d * 16 + fr) * 64;
                bf16x8 v0 = *(const bf16x8*)&vtp[row + pos0];
                bf16x8 v1 = *(const bf16x8*)&vtp[row + pos1];
                acc[s][d] = __builtin_amdgcn_mfma_f32_16x16x32_bf16(aP0, v0, acc[s][d], 0, 0, 0);
                acc[s][d] = __builtin_amdgcn_mfma_f32_16x16x32_bf16(aP1, v1, acc[s][d], 0, 0, 0);
            }
        }
        __builtin_amdgcn_s_setprio(0);
    }

    // epilogue: ctx = acc/(l*128), row = q0 + w*32 + s*16 + quad*4 + r
    #pragma unroll
    for (int s = 0; s < 2; ++s) {
        #pragma unroll
        for (int r = 0; r < 4; ++r) {
            const float scl = 1.0f / (lac[s][r] * 128.0f);
            const long row = (long)b * 2048 + q0 + w * 32 + s * 16 + quad * 4 + r;
            #pragma unroll
            for (int d = 0; d < 4; ++d)
                ctxb[row * 1024 + h * 64 + d * 16 + fr] = f2b(acc[s][d][r] * scl);
        }
    }
}

// ---------------------------------------------------------------------------
extern "C" void kernel_launch(void* const* d_in, const int* in_sizes, int n_in,
                              void* d_out, int out_size, void* d_ws, size_t ws_size,
                              hipStream_t stream) {
    (void)in_sizes; (void)n_in; (void)out_size; (void)ws_size;

    const float* Q  = (const float*)d_in[0];
    const float* K  = (const float*)d_in[1];
    const float* V  = (const float*)d_in[2];
    const float* Wq = (const float*)d_in[3];
    const float* bq = (const float*)d_in[4];
    const float* Wk = (const float*)d_in[5];
    const float* bk = (const float*)d_in[6];
    const float* Wv = (const float*)d_in[7];
    const float* bv = (const float*)d_in[8];
    const float* Wo = (const float*)d_in[9];
    const float* bo = (const float*)d_in[10];
    float* out = (float*)d_out;

    u16* ws  = (u16*)d_ws;                // 64 MB total
    u16* Qb  = ws;                        // 4096x1024
    u16* Kb  = Qb  + 4194304;
    u16* Vb  = Kb  + 4194304;
    u16* WqT = Vb  + 4194304;             // [16][64][1024]
    u16* WkT = WqT + 1048576;
    u16* WvT = WkT + 1048576;
    u16* WoT = WvT + 1048576;             // [1024][1024]
    u16* QWb = WoT + 1048576;             // [32][2048][64]
    u16* KWb = QWb + 4194304;             // [32][2048][64]
    u16* VWb = KWb + 4194304;             // [32][64][2048]
    u16* ctx = VWb + 4194304;             // [4096][1024]

    prep<<<dim3(1024, 1, 5), 256, 0, stream>>>(Q, K, V, Wq, Wk, Wv, Wo,
                                               Qb, Kb, Vb, WqT, WkT, WvT, WoT);

    // grid: x = m-tile (32), y = n-tile (8) for XCD L2 locality
    proj3<<<dim3(32, 8, 3), 256, 0, stream>>>(Qb, Kb, Vb, WqT, WkT, WvT,
                                              bq, bk, bv, QWb, KWb, VWb);

    attn_mfma<<<dim3(16, 32), 256, 0, stream>>>(QWb, KWb, VWb, ctx);

    // 128x64 tiles: grid (32,16) = 512 blocks -> 2 blocks/CU resident
    gemm_out<<<dim3(32, 16), 256, 0, stream>>>(ctx, WoT, bo, out);
}

// Round 13
// 218.278 us; speedup vs baseline: 1.0928x; 1.0021x over previous
//
#include <hip/hip_runtime.h>

typedef unsigned short u16;
typedef unsigned int u32;
typedef __attribute__((ext_vector_type(8))) short bf16x8;
typedef __attribute__((ext_vector_type(4))) float f32x4;

__device__ __forceinline__ u16 f2b(float f) {
    union { float f; u32 u; } v; v.f = f;
    return (u16)((v.u + 0x7FFF + ((v.u >> 16) & 1)) >> 16);  // RNE
}

__device__ __forceinline__ void glds16(const u16* g, u16* l) {
    __builtin_amdgcn_global_load_lds(
        (const __attribute__((address_space(1))) void*)g,
        (__attribute__((address_space(3))) void*)l, 16, 0, 0);
}

// ---------------------------------------------------------------------------
// Fused prep: grid (1024, 1, 4).
//   z<3 : fp32 -> bf16 flat cast of Q/K/V (n4 = 1048576 float4's each).
//   z==3: x<768  -> per-head weight transpose-cast fp32 [16][1024][64]
//                   -> [16][64][1024]  (sel = x>>8, hz = (x>>4)&15);
//         x>=768 -> Wo transpose-cast fp32 [1024][1024] -> ^T (xx = x-768,
//                   256 tiles) — folded into z=3's idle tail (r13).
// Harness INPUTS are cast to bf16 UNMODIFIED (reference quantizes the raw
// inputs). log2(e) fold happens in proj3's fp32 epilogue (r11-proven safe).
// ---------------------------------------------------------------------------
__global__ __launch_bounds__(256) void prep(
    const float* __restrict__ Q, const float* __restrict__ K,
    const float* __restrict__ V,
    const float* __restrict__ Wq, const float* __restrict__ Wk,
    const float* __restrict__ Wv, const float* __restrict__ Wo,
    u16* __restrict__ Qb, u16* __restrict__ Kb, u16* __restrict__ Vb,
    u16* __restrict__ WqT, u16* __restrict__ WkT, u16* __restrict__ WvT,
    u16* __restrict__ WoT)
{
    __shared__ float t[64][68];
    const int z = blockIdx.z, x = blockIdx.x, tid = threadIdx.x;

    if (z < 3) {
        const float* in = (z == 0) ? Q : (z == 1) ? K : V;
        u16* out = (z == 0) ? Qb : (z == 1) ? Kb : Vb;
        const int n4 = 1048576;
        const int stride = 1024 * 256;
        for (int i = x * 256 + tid; i < n4; i += stride) {
            float4 v = ((const float4*)in)[i];
            ushort4 o;
            o.x = f2b(v.x); o.y = f2b(v.y); o.z = f2b(v.z); o.w = f2b(v.w);
            ((ushort4*)out)[i] = o;
        }
        return;
    }

    const int rr = tid >> 4, c4 = (tid & 15) * 4;

    if (x < 768) {
        const int sel = x >> 8, hz = (x >> 4) & 15;
        const float* in = (sel == 0) ? Wq : (sel == 1) ? Wk : Wv;
        u16* out = (sel == 0) ? WqT : (sel == 1) ? WkT : WvT;
        const long mb = (long)hz * 65536;
        const int r0 = (x & 15) * 64;

        #pragma unroll
        for (int p = 0; p < 4; ++p) {
            float4 v = *(const float4*)(in + mb + (long)(r0 + p * 16 + rr) * 64 + c4);
            *(float4*)&t[p * 16 + rr][c4] = v;
        }
        __syncthreads();
        #pragma unroll
        for (int p = 0; p < 4; ++p) {
            const int oc = p * 16 + rr;
            const int r4 = (tid & 15) * 4;
            ushort4 o;
            o.x = f2b(t[r4 + 0][oc]); o.y = f2b(t[r4 + 1][oc]);
            o.z = f2b(t[r4 + 2][oc]); o.w = f2b(t[r4 + 3][oc]);
            *(ushort4*)(out + mb + (long)oc * 1024 + r0 + r4) = o;
        }
        return;
    }

    // x in [768, 1024): Wo transpose tile (xx = x - 768)
    const int xx = x - 768;
    const int r0 = (xx & 15) * 64, c0 = (xx >> 4) * 64;
    #pragma unroll
    for (int p = 0; p < 4; ++p) {
        float4 v = *(const float4*)(Wo + (long)(r0 + p * 16 + rr) * 1024 + c0 + c4);
        *(float4*)&t[p * 16 + rr][c4] = v;
    }
    __syncthreads();
    #pragma unroll
    for (int p = 0; p < 4; ++p) {
        const int oc = p * 16 + rr;
        const int r4 = (tid & 15) * 4;
        ushort4 o;
        o.x = f2b(t[r4 + 0][oc]); o.y = f2b(t[r4 + 1][oc]);
        o.z = f2b(t[r4 + 2][oc]); o.w = f2b(t[r4 + 3][oc]);
        *(ushort4*)(WoT + (long)(c0 + oc) * 1024 + r0 + r4) = o;
    }
}

// ---------------------------------------------------------------------------
// proj3 GEMM body — SINGLE-buffered (r2-proven core: 0 bank conflicts on HW),
// 128x128 tile, 4 waves 2x2, XOR-swizzled LDS chunk^(row&7), BK=64.
// 32 KB LDS -> 3 blocks/CU -> all 768 blocks resident. r12-measured config.
// Grid (32,8,3): x = m-tile for XCD L2 locality (r3-proven). setprio r3-proven.
// ---------------------------------------------------------------------------
#define GEMM_STAGE_SB(A_, BT_, k_)                                             \
    _Pragma("unroll")                                                          \
    for (int i2 = 0; i2 < 4; ++i2) {                                           \
        const int i = w * 4 + i2;                                              \
        glds16(A_ + ga + (long)i * 8 * 1024 + (k_), &As[i * 512]);             \
        glds16(BT_ + gb + (long)i * 8 * 1024 + (k_), &Bs[i * 512]);            \
    }

#define GEMM_CORE_SB(A_, BT_)                                                  \
    __shared__ u16 As[128 * 64];                                               \
    __shared__ u16 Bs[128 * 64];                                               \
    const int tid = threadIdx.x, lane = tid & 63, w = tid >> 6;                \
    const int m0 = blockIdx.x * 128, n0 = blockIdx.y * 128;                    \
    const int wm = (w >> 1) * 64, wn = (w & 1) * 64;                           \
    const int fr = lane & 15, quad = lane >> 4;                                \
    f32x4 acc[4][4];                                                           \
    const f32x4 zero = {0.f, 0.f, 0.f, 0.f};                                   \
    _Pragma("unroll")                                                          \
    for (int mi = 0; mi < 4; ++mi)                                             \
        _Pragma("unroll")                                                      \
        for (int ni = 0; ni < 4; ++ni) acc[mi][ni] = zero;                     \
    const int srow = lane >> 3;                                                \
    const int schk = (lane & 7) ^ (srow & 7);   /* swizzled source chunk */    \
    const long ga = (long)(m0 + srow) * 1024 + schk * 8;                       \
    const long gb = (long)(n0 + srow) * 1024 + schk * 8;                       \
    const int f7 = fr & 7;                                                     \
    for (int k0 = 0; k0 < 1024; k0 += 64) {                                    \
        __syncthreads();                                                       \
        GEMM_STAGE_SB(A_, BT_, k0)                                             \
        __syncthreads();                                                       \
        __builtin_amdgcn_s_setprio(1);                                         \
        _Pragma("unroll")                                                      \
        for (int kc = 0; kc < 2; ++kc) {                                       \
            const int pos = ((kc * 4 + quad) ^ f7) * 8;                        \
            bf16x8 af[4], bfr[4];                                              \
            _Pragma("unroll")                                                  \
            for (int mi = 0; mi < 4; ++mi)                                     \
                af[mi] = *(const bf16x8*)&As[(wm + mi * 16 + fr) * 64 + pos];  \
            _Pragma("unroll")                                                  \
            for (int ni = 0; ni < 4; ++ni)                                     \
                bfr[ni] = *(const bf16x8*)&Bs[(wn + ni * 16 + fr) * 64 + pos]; \
            _Pragma("unroll")                                                  \
            for (int mi = 0; mi < 4; ++mi)                                     \
                _Pragma("unroll")                                              \
                for (int ni = 0; ni < 4; ++ni)                                 \
                    acc[mi][ni] = __builtin_amdgcn_mfma_f32_16x16x32_bf16(     \
                        af[mi], bfr[ni], acc[mi][ni], 0, 0, 0);                \
        }                                                                      \
        __builtin_amdgcn_s_setprio(0);                                         \
    }

// Projections (z: 0=Q, 1=K, 2=V). OUT: z<2 -> [bh][s][64]; z==2 -> [bh][64][s]
// z==0 scaled by log2(e) in fp32 before the bf16 intermediate cast (r11-proven)
__global__ __launch_bounds__(256) void proj3(
    const u16* __restrict__ Qb, const u16* __restrict__ Kb,
    const u16* __restrict__ Vb,
    const u16* __restrict__ WqT, const u16* __restrict__ WkT,
    const u16* __restrict__ WvT,
    const float* __restrict__ bq, const float* __restrict__ bk,
    const float* __restrict__ bv,
    u16* __restrict__ QWb, u16* __restrict__ KWb, u16* __restrict__ VWb)
{
    const int z = blockIdx.z;
    const u16* A  = (z == 0) ? Qb : (z == 1) ? Kb : Vb;
    const u16* BT = (z == 0) ? WqT : (z == 1) ? WkT : WvT;
    const float* bias = (z == 0) ? bq : (z == 1) ? bk : bv;
    u16* Cu = (z == 0) ? QWb : (z == 1) ? KWb : VWb;
    const float scl = (z == 0) ? 1.4426950408889634f : 1.0f;  // log2(e) for Q

    GEMM_CORE_SB(A, BT)

    #pragma unroll
    for (int mi = 0; mi < 4; ++mi) {
        #pragma unroll
        for (int ni = 0; ni < 4; ++ni) {
            const int mB = m0 + wm + mi * 16 + quad * 4;   // r = 0 row
            const int c  = n0 + wn + ni * 16 + fr;
            const int b = mB >> 11, s = mB & 2047, h = c >> 6, k = c & 63;
            const float bi = bias[c];
            if (z != 2) {
                #pragma unroll
                for (int r = 0; r < 4; ++r)
                    Cu[((long)(b * 16 + h) * 2048 + s + r) * 64 + k] =
                        f2b((acc[mi][ni][r] + bi) * scl);
            } else {
                ushort4 o;
                o.x = f2b(acc[mi][ni][0] + bi);
                o.y = f2b(acc[mi][ni][1] + bi);
                o.z = f2b(acc[mi][ni][2] + bi);
                o.w = f2b(acc[mi][ni][3] + bi);
                *(ushort4*)&Cu[((long)(b * 16 + h) * 64 + k) * 2048 + s] = o;
            }
        }
    }
}

// ---------------------------------------------------------------------------
// Output projection: fp32 out = ctx(bf16) @ WoT^T + bo.
// v3: 128x64 tiles, grid (32,16) = 512 blocks (r12), now DOUBLE-buffered
// (r3-proven prefetch pattern): 48 KB LDS — occupancy unchanged (grid caps
// at 2 blocks/CU; 2x48 < 160 KB), tile k+1 loads overlap tile k MFMA.
// Same zero-conflict swizzle. Wave layout 2x2 over (128,64); acc[4][2].
// ---------------------------------------------------------------------------
__global__ __launch_bounds__(256) void gemm_out(
    const u16* __restrict__ A, const u16* __restrict__ BT,
    const float* __restrict__ bias, float* __restrict__ Cf)
{
    __shared__ u16 As[2][128 * 64];   // 32 KB
    __shared__ u16 Bs[2][64 * 64];    // 16 KB

    const int tid = threadIdx.x, lane = tid & 63, w = tid >> 6;
    const int m0 = blockIdx.x * 128, n0 = blockIdx.y * 64;
    const int wm = (w >> 1) * 64, wn = (w & 1) * 32;
    const int fr = lane & 15, quad = lane >> 4;
    f32x4 acc[4][2];
    const f32x4 zero = {0.f, 0.f, 0.f, 0.f};
    #pragma unroll
    for (int mi = 0; mi < 4; ++mi)
        #pragma unroll
        for (int ni = 0; ni < 2; ++ni) acc[mi][ni] = zero;

    const int srow = lane >> 3;
    const int schk = (lane & 7) ^ (srow & 7);   // swizzled source chunk
    const long ga = (long)(m0 + srow) * 1024 + schk * 8;
    const long gb = (long)(n0 + srow) * 1024 + schk * 8;
    const int f7 = fr & 7;

#define GO_STAGE(p_, k_)                                                       \
    _Pragma("unroll")                                                          \
    for (int i2 = 0; i2 < 4; ++i2) {          /* A: 16 chunks, rows 0..127 */  \
        const int i = w * 4 + i2;                                              \
        glds16(A + ga + (long)i * 8 * 1024 + (k_), &As[p_][i * 512]);          \
    }                                                                          \
    _Pragma("unroll")                                                          \
    for (int i2 = 0; i2 < 2; ++i2) {          /* B: 8 chunks, rows 0..63 */    \
        const int i = w * 2 + i2;                                              \
        glds16(BT + gb + (long)i * 8 * 1024 + (k_), &Bs[p_][i * 512]);         \
    }

    GO_STAGE(0, 0)
    __syncthreads();
    for (int k0 = 0; k0 < 1024; k0 += 64) {
        const int p = (k0 >> 6) & 1;
        if (k0 + 64 < 1024) { GO_STAGE(p ^ 1, k0 + 64) }
        __builtin_amdgcn_s_setprio(1);
        #pragma unroll
        for (int kc = 0; kc < 2; ++kc) {
            const int pos = ((kc * 4 + quad) ^ f7) * 8;
            bf16x8 af[4], bfr[2];
            #pragma unroll
            for (int mi = 0; mi < 4; ++mi)
                af[mi] = *(const bf16x8*)&As[p][(wm + mi * 16 + fr) * 64 + pos];
            #pragma unroll
            for (int ni = 0; ni < 2; ++ni)
                bfr[ni] = *(const bf16x8*)&Bs[p][(wn + ni * 16 + fr) * 64 + pos];
            #pragma unroll
            for (int mi = 0; mi < 4; ++mi)
                #pragma unroll
                for (int ni = 0; ni < 2; ++ni)
                    acc[mi][ni] = __builtin_amdgcn_mfma_f32_16x16x32_bf16(
                        af[mi], bfr[ni], acc[mi][ni], 0, 0, 0);
        }
        __builtin_amdgcn_s_setprio(0);
        __syncthreads();
    }
#undef GO_STAGE

    #pragma unroll
    for (int mi = 0; mi < 4; ++mi) {
        #pragma unroll
        for (int ni = 0; ni < 2; ++ni) {
            #pragma unroll
            for (int r = 0; r < 4; ++r) {
                const int m = m0 + wm + mi * 16 + quad * 4 + r;
                const int c = n0 + wn + ni * 16 + fr;
                Cf[(long)m * 1024 + c] = acc[mi][ni][r] + bias[c];
            }
        }
    }
}

// ---------------------------------------------------------------------------
// MFMA flash attention — round-11/12 passing version (byte-identical).
//   QW (log2e-prescaled)/KW: [bh][2048][64]; VW: [bh][64][2048] (bf16).
//   Block = 4 waves, 128 q rows. Distance-2 prefetch over 3 LDS buffers,
//   counted vmcnt(4) + raw s_barrier. XCD colocate remap. exp via raw
//   v_exp_f32. ps LINEAR stride-72 (XOR relayout HW-failed r5/r6 — burned).
//   Swapped QK^T -> cvt_pk + b64 P store; setprio; l via ones-MFMA;
//   ctx scaled by 1/(l*128).
// ---------------------------------------------------------------------------
__global__ __launch_bounds__(256) void attn_mfma(
    const u16* __restrict__ QW, const u16* __restrict__ KW,
    const u16* __restrict__ VW, u16* __restrict__ ctxb)
{
    __shared__ u16 kt[3][64 * 64];   // [buf][t][k] swizzled, 24 KB
    __shared__ u16 vt[3][64 * 64];   // [buf][d][t] swizzled, 24 KB
    __shared__ u16 ps[4][32 * 72];   // per-wave P [q][t], stride 72, 18 KB

    const int tid = threadIdx.x, lane = tid & 63, w = tid >> 6;
    const int id = blockIdx.x + gridDim.x * blockIdx.y;
    const int bh = (id & 7) * 4 + ((id >> 3) & 3);
    const int q0 = (id >> 5) * 128;
    const int b = bh >> 4, h = bh & 15;
    const int fr = lane & 15, quad = lane >> 4;
    const int f7 = fr & 7;

    bf16x8 aQ[2][2];
    #pragma unroll
    for (int s = 0; s < 2; ++s) {
        const u16* qp = QW + ((long)bh * 2048 + q0 + w * 32 + s * 16 + fr) * 64;
        aQ[s][0] = *(const bf16x8*)(qp + quad * 8);
        aQ[s][1] = *(const bf16x8*)(qp + 32 + quad * 8);
    }

    const f32x4 zero = {0.f, 0.f, 0.f, 0.f};
    f32x4 acc[2][4], lac[2];
    #pragma unroll
    for (int s = 0; s < 2; ++s) {
        lac[s] = zero;
        #pragma unroll
        for (int d = 0; d < 4; ++d) acc[s][d] = zero;
    }
    bf16x8 bones;
    #pragma unroll
    for (int j = 0; j < 8; ++j) bones[j] = (short)0x3F80;  // bf16 1.0

    const int srow = lane >> 3;
    const int schk = (lane & 7) ^ (srow & 7);   // swizzled source chunk
    const long kgb = (long)bh * (2048 * 64);
    const long vgb = (long)bh * (64 * 2048);

#define ATTN_STAGE(p_, t_)                                                    \
    _Pragma("unroll")                                                         \
    for (int i2 = 0; i2 < 2; ++i2) {                                          \
        const int i = w * 2 + i2;                                             \
        glds16(KW + kgb + (long)((t_) + i * 8 + srow) * 64 + schk * 8,        \
               &kt[p_][i * 512]);                                             \
        glds16(VW + vgb + (long)(i * 8 + srow) * 2048 + (t_) + schk * 8,      \
               &vt[p_][i * 512]);                                             \
    }

    ATTN_STAGE(0, 0)
    ATTN_STAGE(1, 64)

    const int pos0 = (quad ^ f7) * 8;      // swizzled chunk {quad}
    const int pos1 = pos0 ^ 32;            // swizzled chunk {quad+4}
    u16* pw = ps[w];

    for (int t0 = 0; t0 < 2048; t0 += 64) {
        const int it = t0 >> 6;
        const int p = it % 3;

        if (t0 + 64 < 2048) {
            __asm__ volatile("s_waitcnt vmcnt(4)" ::: "memory");
        } else {
            __asm__ volatile("s_waitcnt vmcnt(0)" ::: "memory");
        }
        __builtin_amdgcn_s_barrier();
        __asm__ volatile("" ::: "memory");
        __builtin_amdgcn_sched_barrier(0);

        if (t0 + 128 < 2048) { ATTN_STAGE((it + 2) % 3, t0 + 128) }

        const u16* ktp = kt[p];
        const u16* vtp = vt[p];

        // ---- swapped QK^T: D[t][q]; lane(fr=q,quad): t = sub*16+quad*4+r
        f32x4 sc[2][4];
        __builtin_amdgcn_s_setprio(1);
        #pragma unroll
        for (int s = 0; s < 2; ++s) {
            #pragma unroll
            for (int sub = 0; sub < 4; ++sub) {
                const int row = (sub * 16 + fr) * 64;
                bf16x8 k0 = *(const bf16x8*)&ktp[row + pos0];
                bf16x8 k1 = *(const bf16x8*)&ktp[row + pos1];
                f32x4 z = __builtin_amdgcn_mfma_f32_16x16x32_bf16(k0, aQ[s][0], zero, 0, 0, 0);
                sc[s][sub] = __builtin_amdgcn_mfma_f32_16x16x32_bf16(k1, aQ[s][1], z, 0, 0, 0);
            }
        }
        __builtin_amdgcn_s_setprio(0);

        // ---- exp2 + packed bf16 convert + vectorized P store (b64) ----
        #pragma unroll
        for (int s = 0; s < 2; ++s) {
            #pragma unroll
            for (int sub = 0; sub < 4; ++sub) {
                float e0 = __builtin_amdgcn_exp2f(sc[s][sub][0]);
                float e1 = __builtin_amdgcn_exp2f(sc[s][sub][1]);
                float e2 = __builtin_amdgcn_exp2f(sc[s][sub][2]);
                float e3 = __builtin_amdgcn_exp2f(sc[s][sub][3]);
                u32 lo, hi;
                asm("v_cvt_pk_bf16_f32 %0, %1, %2" : "=v"(lo) : "v"(e0), "v"(e1));
                asm("v_cvt_pk_bf16_f32 %0, %1, %2" : "=v"(hi) : "v"(e2), "v"(e3));
                uint2 pk2; pk2.x = lo; pk2.y = hi;
                *(uint2*)&pw[(s * 16 + fr) * 72 + sub * 16 + quad * 4] = pk2;
            }
        }
        __asm__ volatile("s_waitcnt lgkmcnt(0)" ::: "memory");

        // ---- l (ones-MFMA) + PV for both q-sets ----
        __builtin_amdgcn_s_setprio(1);
        #pragma unroll
        for (int s = 0; s < 2; ++s) {
            const bf16x8 aP0 = *(const bf16x8*)&pw[(s * 16 + fr) * 72 + quad * 8];
            const bf16x8 aP1 = *(const bf16x8*)&pw[(s * 16 + fr) * 72 + 32 + quad * 8];
            lac[s] = __builtin_amdgcn_mfma_f32_16x16x32_bf16(aP0, bones, lac[s], 0, 0, 0);
            lac[s] = __builtin_amdgcn_mfma_f32_16x16x32_bf16(aP1, bones, lac[s], 0, 0, 0);
            #pragma unroll
            for (int d = 0; d < 4; ++d) {
                const int row = (d * 16 + fr) * 64;
                bf16x8 v0 = *(const bf16x8*)&vtp[row + pos0];
                bf16x8 v1 = *(const bf16x8*)&vtp[row + pos1];
                acc[s][d] = __builtin_amdgcn_mfma_f32_16x16x32_bf16(aP0, v0, acc[s][d], 0, 0, 0);
                acc[s][d] = __builtin_amdgcn_mfma_f32_16x16x32_bf16(aP1, v1, acc[s][d], 0, 0, 0);
            }
        }
        __builtin_amdgcn_s_setprio(0);
    }

    // epilogue: ctx = acc/(l*128), row = q0 + w*32 + s*16 + quad*4 + r
    #pragma unroll
    for (int s = 0; s < 2; ++s) {
        #pragma unroll
        for (int r = 0; r < 4; ++r) {
            const float scl = 1.0f / (lac[s][r] * 128.0f);
            const long row = (long)b * 2048 + q0 + w * 32 + s * 16 + quad * 4 + r;
            #pragma unroll
            for (int d = 0; d < 4; ++d)
                ctxb[row * 1024 + h * 64 + d * 16 + fr] = f2b(acc[s][d][r] * scl);
        }
    }
}

// ---------------------------------------------------------------------------
extern "C" void kernel_launch(void* const* d_in, const int* in_sizes, int n_in,
                              void* d_out, int out_size, void* d_ws, size_t ws_size,
                              hipStream_t stream) {
    (void)in_sizes; (void)n_in; (void)out_size; (void)ws_size;

    const float* Q  = (const float*)d_in[0];
    const float* K  = (const float*)d_in[1];
    const float* V  = (const float*)d_in[2];
    const float* Wq = (const float*)d_in[3];
    const float* bq = (const float*)d_in[4];
    const float* Wk = (const float*)d_in[5];
    const float* bk = (const float*)d_in[6];
    const float* Wv = (const float*)d_in[7];
    const float* bv = (const float*)d_in[8];
    const float* Wo = (const float*)d_in[9];
    const float* bo = (const float*)d_in[10];
    float* out = (float*)d_out;

    u16* ws  = (u16*)d_ws;                // 64 MB total
    u16* Qb  = ws;                        // 4096x1024
    u16* Kb  = Qb  + 4194304;
    u16* Vb  = Kb  + 4194304;
    u16* WqT = Vb  + 4194304;             // [16][64][1024]
    u16* WkT = WqT + 1048576;
    u16* WvT = WkT + 1048576;
    u16* WoT = WvT + 1048576;             // [1024][1024]
    u16* QWb = WoT + 1048576;             // [32][2048][64]
    u16* KWb = QWb + 4194304;             // [32][2048][64]
    u16* VWb = KWb + 4194304;             // [32][64][2048]
    u16* ctx = VWb + 4194304;             // [4096][1024]

    prep<<<dim3(1024, 1, 4), 256, 0, stream>>>(Q, K, V, Wq, Wk, Wv, Wo,
                                               Qb, Kb, Vb, WqT, WkT, WvT, WoT);

    // grid: x = m-tile (32), y = n-tile (8) for XCD L2 locality
    proj3<<<dim3(32, 8, 3), 256, 0, stream>>>(Qb, Kb, Vb, WqT, WkT, WvT,
                                              bq, bk, bv, QWb, KWb, VWb);

    attn_mfma<<<dim3(16, 32), 256, 0, stream>>>(QWb, KWb, VWb, ctx);

    // 128x64 tiles: grid (32,16) = 512 blocks, double-buffered
    gemm_out<<<dim3(32, 16), 256, 0, stream>>>(ctx, WoT, bo, out);
}